// Round 1
// baseline (1289.922 us; speedup 1.0000x reference)
//
#include <hip/hip_runtime.h>
#include <hip/hip_bf16.h>

#define K 5
#define F 64
#define EMBD 200
#define HID 256
#define NH 3
#define NL 3
#define CB 8            // crystals per block for POOL kernels
#define NB (CB * K)     // 40 nodes per pool block

// layer kernel: 4 waves x 3 crystals = 12 crystals / block
#define CW 3            // crystals per wave
#define NWN (CW * K)    // 15 nodes per wave
#define EWE (CW * K * K) // 75 edges per wave
#define ET 5            // edge tiles of 16

typedef _Float16 half8 __attribute__((ext_vector_type(8)));
typedef float f32x4 __attribute__((ext_vector_type(4)));

__device__ __forceinline__ float lrelu(float v) { return v >= 0.f ? v : 0.01f * v; }

__device__ __forceinline__ half8 lrelu8(half8 t) {
    half8 z = 0;
    half8 p = __builtin_elementwise_max(t, z);
    half8 n = __builtin_elementwise_min(t, z);
    return p + n * (_Float16)0.01f;
}

// ---- swizzled-weight element counts (fp16) ----
#define W1SW_ELEMS 589824    // 9 lh * 2 net * 2 half * 4 chunk * 4 nt * 2 ks * 64 * 8
#define W2SW_ELEMS 147456    // 9 lh * 8 ks2 * 4 nt * 64 * 8
#define CW1_ELEMS   98304    // 3 h * 2 net * 4 chunk * 4 nt * 2 ks * 64 * 8
#define CW2_ELEMS   49152    // 3 h * 8 ks2 * 4 nt * 64 * 8
#define WALL_ELEMS (W1SW_ELEMS + W2SW_ELEMS + CW1_ELEMS + CW2_ELEMS)  // 884736

// per-layer (fallback) sizes
#define W1L_ELEMS 196608
#define W2L_ELEMS 49152

// gate W2 fp16 copy: 9 lh * 256
#define WG_ELEMS (NL * NH * HID)

// ---------------------------------------------------------------------------
// Fast path: swizzle ALL weights (layers + pool) fp32 -> fp16 B-frag order.
// ---------------------------------------------------------------------------
__global__ __launch_bounds__(256)
void prep_all(const float* __restrict__ gW1, const float* __restrict__ mW1,
              const float* __restrict__ mW2,
              const float* __restrict__ cgW1, const float* __restrict__ cmW1,
              const float* __restrict__ cmW2,
              _Float16* __restrict__ Wall)
{
    int tid = blockIdx.x * 256 + threadIdx.x;
    if (tid >= WALL_ELEMS) return;
    float v;
    if (tid < W1SW_ELEMS) {
        int j = tid & 7, lane = (tid >> 3) & 63;
        int r1 = tid >> 9;                       // [lh][net][half][chunk][nt][ks]
        int ks = r1 & 1, nt = (r1 >> 1) & 3, chunk = (r1 >> 3) & 3;
        int half = (r1 >> 5) & 1, net = (r1 >> 6) & 1, lh = r1 >> 7;   // 0..8
        int q = lane >> 4, n16 = lane & 15;
        const float* src = net ? mW1 : gW1;
        v = src[((size_t)lh * 128 + half * 64 + ks * 32 + q * 8 + j) * 256
                + chunk * 64 + nt * 16 + n16];
    } else if (tid < W1SW_ELEMS + W2SW_ELEMS) {
        int t2 = tid - W1SW_ELEMS;
        int j = t2 & 7, lane = (t2 >> 3) & 63;
        int r1 = t2 >> 9;                        // [lh][ks2][nt]
        int nt = r1 & 3, ks2 = (r1 >> 2) & 7, lh = r1 >> 5;            // 0..8
        int q = lane >> 4, n16 = lane & 15;
        v = mW2[((size_t)lh * 256 + ks2 * 32 + q * 8 + j) * 64 + nt * 16 + n16];
    } else if (tid < W1SW_ELEMS + W2SW_ELEMS + CW1_ELEMS) {
        int t2 = tid - (W1SW_ELEMS + W2SW_ELEMS);
        int j = t2 & 7, lane = (t2 >> 3) & 63;
        int r1 = t2 >> 9;                        // [h][net][chunk][nt][ks]
        int ks = r1 & 1, nt = (r1 >> 1) & 3, chunk = (r1 >> 3) & 3;
        int net = (r1 >> 5) & 1, h = r1 >> 6;                          // 0..2
        int q = lane >> 4, n16 = lane & 15;
        const float* src = net ? cmW1 : cgW1;
        v = src[((size_t)h * 64 + ks * 32 + q * 8 + j) * 256
                + chunk * 64 + nt * 16 + n16];
    } else {
        int t2 = tid - (W1SW_ELEMS + W2SW_ELEMS + CW1_ELEMS);
        int j = t2 & 7, lane = (t2 >> 3) & 63;
        int r1 = t2 >> 9;                        // [h][ks2][nt]
        int nt = r1 & 3, ks2 = (r1 >> 2) & 7, h = r1 >> 5;             // 0..2
        int q = lane >> 4, n16 = lane & 15;
        v = cmW2[((size_t)h * 256 + ks2 * 32 + q * 8 + j) * 64 + nt * 16 + n16];
    }
    Wall[tid] = (_Float16)v;
}

// gate-W2 fp32 -> fp16 straight copy (B-frag built in-kernel by masking)
__global__ __launch_bounds__(256)
void prep_wg(const float* __restrict__ gW2, _Float16* __restrict__ wgh)
{
    int tid = blockIdx.x * 256 + threadIdx.x;
    if (tid < WG_ELEMS) wgh[tid] = (_Float16)gW2[tid];
}

// ---------------------------------------------------------------------------
// Fallback: per-layer prep into d_out scratch (round-4 proven).
// ---------------------------------------------------------------------------
__global__ __launch_bounds__(256)
void prep_layer(const float* __restrict__ gW1, const float* __restrict__ mW1,
                const float* __restrict__ mW2,
                _Float16* __restrict__ W1sw, _Float16* __restrict__ W2sw, int l)
{
    int tid = blockIdx.x * 256 + threadIdx.x;
    if (tid < W1L_ELEMS) {
        int j = tid & 7, lane = (tid >> 3) & 63;
        int r1 = tid >> 9;
        int ks = r1 & 1, nt = (r1 >> 1) & 3, chunk = (r1 >> 3) & 3;
        int half = (r1 >> 5) & 1, net = (r1 >> 6) & 1, hh = r1 >> 7;
        int q = lane >> 4, n16 = lane & 15;
        const float* src = net ? mW1 : gW1;
        float v = src[((size_t)(l * NH + hh) * 128 + half * 64 + ks * 32 + q * 8 + j) * 256
                      + chunk * 64 + nt * 16 + n16];
        W1sw[tid] = (_Float16)v;
    } else {
        int t2 = tid - W1L_ELEMS;
        if (t2 < W2L_ELEMS) {
            int j = t2 & 7, lane = (t2 >> 3) & 63;
            int r1 = t2 >> 9;
            int nt = r1 & 3, ks2 = (r1 >> 2) & 7, hh = r1 >> 5;
            int q = lane >> 4, n16 = lane & 15;
            float v = mW2[((size_t)(l * NH + hh) * 256 + ks2 * 32 + q * 8 + j) * 64
                          + nt * 16 + n16];
            W2sw[t2] = (_Float16)v;
        }
    }
}

// ---------------------------------------------------------------------------
// Embedding
// ---------------------------------------------------------------------------
__global__ __launch_bounds__(64)
void embed_kernel(const float* __restrict__ fea, const float* __restrict__ W,
                  const float* __restrict__ b, const float* __restrict__ wts,
                  float* __restrict__ x)
{
    int n = blockIdx.x;
    int o = threadIdx.x;
    __shared__ float fs[EMBD];
    for (int e = o; e < EMBD; e += 64) fs[e] = fea[n * EMBD + e];
    __syncthreads();
    if (o < F - 1) {
        float acc = b[o];
#pragma unroll 8
        for (int e = 0; e < EMBD; ++e) acc += fs[e] * W[e * (F - 1) + o];
        x[n * F + o] = acc;
    } else {
        x[n * F + F - 1] = wts[n];
    }
}

// ---------------------------------------------------------------------------
// One graph layer — barrier-free, 4 independent waves / block, each wave owns
// 3 crystals (15 nodes, 75 edges). GEMM2 B-frags hoisted (loaded once per
// chunk, reused by 5 edge-tiles). Wave-private LDS slice 12288 B.
// __launch_bounds__(256) only: round 7's (256,3) pin capped VGPRs at 84 and
// spilled the MFMA accumulators to scratch (147 MB/dispatch HBM writes).
//
// Round 8: VALU diet for the latency-bound consume phase:
//  - gate dot-product -> rank-1 MFMA (tg is already A-frag layout; wgB is a
//    col-0-only B-frag from fp16 gate weights). Kills 32 scalar cvt+fma per
//    (et,chunk) and the shfl_xor gate reduce.
//  - stage-1 bias folded into the P-half MFMA accumulator init (C-in is
//    additive), removing per-(et,ks) bias adds + per-chunk bias frag builds.
//  - mb2 folded into acc2 init, removing the +b2v in the msgL write.
// ---------------------------------------------------------------------------
#define WAVE_LDS 12288   // bytes per wave slice

__global__ __launch_bounds__(256)
void layer_wave(float* __restrict__ x,
                const _Float16* __restrict__ W1sw,
                const _Float16* __restrict__ W2sw,
                const float* __restrict__ gb1, const float* __restrict__ gb2v,
                const float* __restrict__ mb1, const float* __restrict__ mb2,
                const _Float16* __restrict__ wgh, const float* __restrict__ gpw,
                const float* __restrict__ wts, int l, int lhw0, int Ntot)
{
    __shared__ __align__(16) char smem[4 * WAVE_LDS];

    const int t = threadIdx.x, w = t >> 6, lane = t & 63;
    const int q = lane >> 4, m16 = lane & 15;

    char* wb = smem + w * WAVE_LDS;
    _Float16 (*PQ)[16][72] = (_Float16 (*)[16][72])wb;   // [4][16][72] = 9216 B
    _Float16 (*msgL)[72]   = (_Float16 (*)[72])wb;       // [80][72] = 11520 B (aliases PQ)
    float* gateS  = (float*)(wb + 11520);                // [80]
    float* anormS = (float*)(wb + 11840);                // [80]
    float* wpowS  = (float*)(wb + 12160);                // [16]

    const int nw0 = (blockIdx.x * 12 + w * CW) * K;      // first node of this wave
    const int vn  = (Ntot - nw0 < NWN) ? (Ntot - nw0) : NWN;  // valid nodes (may be <=0)

    // ---- A-fragments of x (head/half-invariant), fp16, loaded once ----
    half8 A[2];
    {
        int arow = nw0 + m16;
        if (arow > Ntot - 1) arow = Ntot - 1;            // clamp pad rows (finite junk)
        if (arow < 0) arow = 0;
        const float* xr = x + (size_t)arow * F;
#pragma unroll
        for (int ks = 0; ks < 2; ++ks) {
            float4 f0 = *(const float4*)(xr + ks * 32 + q * 8);
            float4 f1 = *(const float4*)(xr + ks * 32 + q * 8 + 4);
            half8 a;
            a[0] = (_Float16)f0.x; a[1] = (_Float16)f0.y;
            a[2] = (_Float16)f0.z; a[3] = (_Float16)f0.w;
            a[4] = (_Float16)f1.x; a[5] = (_Float16)f1.y;
            a[6] = (_Float16)f1.z; a[7] = (_Float16)f1.w;
            A[ks] = a;
        }
    }

    // ---- per-lane edge -> local node rows (75 valid edges in 5 tiles of 16) ----
    int iR[ET], jR[ET];
#pragma unroll
    for (int et = 0; et < ET; ++et) {
        int e = et * 16 + m16;
        if (e < EWE) {
            int cl = e / 25, rm = e % 25;
            iR[et] = cl * K + rm / K;
            jR[et] = cl * K + rm % K;
        } else { iR[et] = 15; jR[et] = 15; }             // pad row (clamped x, finite)
    }

    float oacc[NWN];
#pragma unroll
    for (int n = 0; n < NWN; ++n) oacc[n] = 0.f;

    for (int h = 0; h < NH; ++h) {
        const int lh = l * NH + h, lhw = lhw0 + h;

        if (lane < NWN) {
            int wi = nw0 + lane;
            if (wi > Ntot - 1) wi = Ntot - 1;
            if (wi < 0) wi = 0;
            wpowS[lane] = powf(wts[wi], gpw[lh]);
        }
        if (lane >= NWN && lane < NWN + 5) anormS[EWE + (lane - NWN)] = 0.f;  // pad slots 75..79

        // msg output bias (per output col = m16), folded into acc2 init
        float b2v[4];
#pragma unroll
        for (int nt = 0; nt < 4; ++nt) b2v[nt] = mb2[(size_t)lh * F + nt * 16 + m16];

        f32x4 acc2[ET][4];
#pragma unroll
        for (int et = 0; et < ET; ++et)
#pragma unroll
            for (int nt = 0; nt < 4; ++nt)
                acc2[et][nt] = (f32x4){b2v[nt], b2v[nt], b2v[nt], b2v[nt]};
        f32x4 gAcc[ET];
#pragma unroll
        for (int et = 0; et < ET; ++et) gAcc[et] = (f32x4){0.f, 0.f, 0.f, 0.f};

        for (int c = 0; c < 4; ++c) {
            // ---- GEMM2 B-frags for this chunk: issue early, reuse for 5 et ----
            half8 B2[8];
            {
                const _Float16* W2b = W2sw + ((size_t)lhw * 8 + c * 2) * 2048;
#pragma unroll
                for (int f = 0; f < 8; ++f)
                    B2[f] = *(const half8*)(W2b + ((size_t)f * 64 + lane) * 8);
            }

            // ---- gate-W2 B-frags: col 0 only (lanes m16==0 carry weights) ----
            half8 wgB[2];
            {
                half8 hz = 0;
#pragma unroll
                for (int ks = 0; ks < 2; ++ks) {
                    half8 w8 = *(const half8*)(wgh + (size_t)lh * HID + c * 64
                                               + ks * 32 + q * 8);
                    wgB[ks] = (m16 == 0) ? w8 : hz;
                }
            }

            // ---- stage-1 biases for the P halves (C layout: col = m16) ----
            float bg4[4], bm4[4];
#pragma unroll
            for (int nt = 0; nt < 4; ++nt) {
                bg4[nt] = gb1[(size_t)lh * HID + c * 64 + nt * 16 + m16];
                bm4[nt] = mb1[(size_t)lh * HID + c * 64 + nt * 16 + m16];
            }

            // ---- stage-1: all 4 net-halves (0:Pg 1:Qg 2:Pm 3:Qm) ----
#pragma unroll
            for (int hf = 0; hf < 4; ++hf) {
                f32x4 accS[4];
#pragma unroll
                for (int nt = 0; nt < 4; ++nt) {
                    float bi = (hf == 0) ? bg4[nt] : (hf == 2) ? bm4[nt] : 0.f;
                    accS[nt] = (f32x4){bi, bi, bi, bi};
                }
                const _Float16* Wb = W1sw + ((size_t)lhw * 4 + hf) * 16384 + c * 4096;
#pragma unroll
                for (int nt = 0; nt < 4; ++nt)
#pragma unroll
                    for (int ks = 0; ks < 2; ++ks) {
                        half8 B = *(const half8*)(Wb + ((nt * 2 + ks) * 64 + lane) * 8);
                        accS[nt] = __builtin_amdgcn_mfma_f32_16x16x32_f16(
                            A[ks], B, accS[nt], 0, 0, 0);
                    }
#pragma unroll
                for (int nt = 0; nt < 4; ++nt)
#pragma unroll
                    for (int rg = 0; rg < 4; ++rg)
                        PQ[hf][q * 4 + rg][nt * 16 + m16] = (_Float16)accS[nt][rg];
            }

            // ---- consume: gate MFMA + hm A-frags + GEMM2 (B2 reused) ----
#pragma unroll
            for (int et = 0; et < ET; ++et) {
                half8 af[2], tg2[2];
#pragma unroll
                for (int ks = 0; ks < 2; ++ks) {
                    const int ub = ks * 32 + q * 8;
                    half8 pg = *(const half8*)&PQ[0][iR[et]][ub];
                    half8 qg = *(const half8*)&PQ[1][jR[et]][ub];
                    half8 pm = *(const half8*)&PQ[2][iR[et]][ub];
                    half8 qm = *(const half8*)&PQ[3][jR[et]][ub];
                    tg2[ks] = lrelu8(pg + qg);           // bias folded into P
                    af[ks]  = lrelu8(pm + qm);
                }
#pragma unroll
                for (int ks = 0; ks < 2; ++ks)
                    gAcc[et] = __builtin_amdgcn_mfma_f32_16x16x32_f16(
                        tg2[ks], wgB[ks], gAcc[et], 0, 0, 0);
#pragma unroll
                for (int nt = 0; nt < 4; ++nt)
#pragma unroll
                    for (int ks = 0; ks < 2; ++ks)
                        acc2[et][nt] = __builtin_amdgcn_mfma_f32_16x16x32_f16(
                            af[ks], B2[ks * 4 + nt], acc2[et][nt], 0, 0, 0);
            }
        }

        // ---- gate write: D col 0 lives in lanes m16==0, row = q*4+rg ----
        const float gb2s = gb2v[lh];
        if (m16 == 0) {
#pragma unroll
            for (int et = 0; et < ET; ++et)
#pragma unroll
                for (int rg = 0; rg < 4; ++rg)
                    gateS[et * 16 + q * 4 + rg] = gAcc[et][rg] + gb2s;
        }

        // ---- segment softmax: lane n (0..14) handles local node n (5 edges) ----
        if (lane < NWN) {
            const int cl5 = (lane / K) * K;
            float gg[K], mx = -1e30f;
#pragma unroll
            for (int jj = 0; jj < K; ++jj) {
                gg[jj] = gateS[lane * K + jj];
                mx = fmaxf(mx, gg[jj]);
            }
            float s = 0.f, wv[K];
#pragma unroll
            for (int jj = 0; jj < K; ++jj) {
                wv[jj] = wpowS[cl5 + jj] * expf(gg[jj] - mx);
                s += wv[jj];
            }
            float inv = 1.f / (s + 1e-10f) * (1.f / 3.f);  // fold head mean
#pragma unroll
            for (int jj = 0; jj < K; ++jj) anormS[lane * K + jj] = wv[jj] * inv;
        }

        // ---- weighted msg -> msgL (PQ region dead); mb2 already in acc2 ----
#pragma unroll
        for (int et = 0; et < ET; ++et) {
            f32x4 an = *(const f32x4*)&anormS[et * 16 + q * 4];
#pragma unroll
            for (int nt = 0; nt < 4; ++nt)
#pragma unroll
                for (int rg = 0; rg < 4; ++rg) {
                    float v = acc2[et][nt][rg] * an[rg];
                    msgL[et * 16 + q * 4 + rg][nt * 16 + m16] = (_Float16)v;
                }
        }

        // ---- aggregate: lane = output col, 15 nodes x 5 edges ----
#pragma unroll
        for (int n = 0; n < NWN; ++n) {
            float s = 0.f;
#pragma unroll
            for (int jj = 0; jj < K; ++jj) s += (float)msgL[n * K + jj][lane];
            oacc[n] += s;
        }
    }

    // ---- residual + write back (own valid rows only) ----
#pragma unroll
    for (int n = 0; n < NWN; ++n) {
        if (n < vn) {
            size_t idx = (size_t)(nw0 + n) * F + lane;
            x[idx] = oacc[n] + x[idx];
        }
    }
}

// ---------------------------------------------------------------------------
// MFMA pool (round-5 proven)
// ---------------------------------------------------------------------------
__global__ __launch_bounds__(256)
void pool_mfma(const float* __restrict__ x,
               const _Float16* __restrict__ cW1sw,
               const _Float16* __restrict__ cW2sw,
               const float* __restrict__ cgb1, const float* __restrict__ cgb2v,
               const float* __restrict__ cmb1, const float* __restrict__ cmb2,
               const float* __restrict__ cgW2, const float* __restrict__ cpw,
               const float* __restrict__ wts, float* __restrict__ out)
{
    __shared__ __align__(16) _Float16 xh[48][72];
    __shared__ __align__(16) char PQraw[2 * 48 * 72 * 2];
    __shared__ float outacc[CB * F];
    __shared__ float b1gS[HID], b1mS[HID], w2gS[HID], b2mS[F];
    __shared__ float gateS[48], anormS[48], wpowS[48];

    _Float16 (*P)[48][72] = (_Float16 (*)[48][72])PQraw;
    _Float16 (*msgW)[72]  = (_Float16 (*)[72])PQraw;

    const int t = threadIdx.x, w = t >> 6, lane = t & 63;
    const int quad = lane >> 4, m16 = lane & 15;
    const int node0 = blockIdx.x * NB;

    for (int d = t; d < 48 * 64; d += 256) {
        int r = d >> 6, cc = d & 63;
        float v = (r < NB) ? x[(size_t)(node0 + r) * F + cc] : 0.f;
        xh[r][cc] = (_Float16)v;
    }
    for (int d = t; d < CB * F; d += 256) outacc[d] = 0.f;
    __syncthreads();

    half8 A[3][2];
#pragma unroll
    for (int Mt = 0; Mt < 3; ++Mt)
#pragma unroll
        for (int ks = 0; ks < 2; ++ks)
            A[Mt][ks] = *(const half8*)&xh[Mt * 16 + m16][ks * 32 + quad * 8];

    const int net = w >> 1, ntp = w & 1;

    for (int h = 0; h < NH; ++h) {
        if (t < HID) {
            b1gS[t] = cgb1[(size_t)h * HID + t];
            b1mS[t] = cmb1[(size_t)h * HID + t];
            w2gS[t] = cgW2[(size_t)h * HID + t];
        }
        if (t < F)  b2mS[t] = cmb2[(size_t)h * F + t];
        if (t < NB) wpowS[t] = powf(wts[node0 + t], cpw[h]);
        const float gb2s = cgb2v[h];

        f32x4 acc2[4];
#pragma unroll
        for (int nt = 0; nt < 4; ++nt) acc2[nt] = (f32x4){0.f, 0.f, 0.f, 0.f};
        float gacc = 0.f;

        for (int chunk = 0; chunk < 4; ++chunk) {
            {
                f32x4 accS[3][2];
#pragma unroll
                for (int Mt = 0; Mt < 3; ++Mt)
#pragma unroll
                    for (int n2 = 0; n2 < 2; ++n2) accS[Mt][n2] = (f32x4){0.f, 0.f, 0.f, 0.f};
                const _Float16* Wb = cW1sw + ((size_t)(h * 2 + net) * 4 + chunk) * 4096;
#pragma unroll
                for (int n2 = 0; n2 < 2; ++n2) {
                    int nt = ntp * 2 + n2;
#pragma unroll
                    for (int ks = 0; ks < 2; ++ks) {
                        half8 B = *(const half8*)(Wb + ((nt * 2 + ks) * 64 + lane) * 8);
#pragma unroll
                        for (int Mt = 0; Mt < 3; ++Mt)
                            accS[Mt][n2] = __builtin_amdgcn_mfma_f32_16x16x32_f16(
                                A[Mt][ks], B, accS[Mt][n2], 0, 0, 0);
                    }
                }
#pragma unroll
                for (int Mt = 0; Mt < 3; ++Mt)
#pragma unroll
                    for (int n2 = 0; n2 < 2; ++n2)
#pragma unroll
                        for (int rg = 0; rg < 4; ++rg)
                            P[net][Mt * 16 + quad * 4 + rg][(ntp * 2 + n2) * 16 + m16] =
                                (_Float16)accS[Mt][n2][rg];
            }
            __syncthreads();

            if (w < 3) {
                half8 af[2];
#pragma unroll
                for (int ks = 0; ks < 2; ++ks) {
                    const int ub = ks * 32 + quad * 8;
                    half8 pg = *(const half8*)&P[0][w * 16 + m16][ub];
                    half8 pm = *(const half8*)&P[1][w * 16 + m16][ub];
#pragma unroll
                    for (int j = 0; j < 8; ++j) {
                        int u = chunk * 64 + ub + j;
                        float gh = lrelu((float)pg[j] + b1gS[u]);
                        gacc += gh * w2gS[u];
                        float hv = lrelu((float)pm[j] + b1mS[u]);
                        af[ks][j] = (_Float16)hv;
                    }
                }
                const _Float16* W2b = cW2sw + (size_t)h * 16384 + chunk * 4096;
#pragma unroll
                for (int nt = 0; nt < 4; ++nt)
#pragma unroll
                    for (int ks = 0; ks < 2; ++ks) {
                        half8 B = *(const half8*)(W2b + ((size_t)(ks * 4 + nt) * 64 + lane) * 8);
                        acc2[nt] = __builtin_amdgcn_mfma_f32_16x16x32_f16(
                            af[ks], B, acc2[nt], 0, 0, 0);
                    }
            }
            __syncthreads();
        }

        if (w < 3) {
            float g = gacc;
            g += __shfl_xor(g, 16);
            g += __shfl_xor(g, 32);
            if (quad == 0) gateS[w * 16 + m16] = g + gb2s;
        }
        __syncthreads();

        if (t < CB) {
            float mx = -1e30f;
#pragma unroll
            for (int j = 0; j < K; ++j) mx = fmaxf(mx, gateS[t * K + j]);
            float s = 0.f, wv[K];
#pragma unroll
            for (int j = 0; j < K; ++j) {
                wv[j] = wpowS[t * K + j] * expf(gateS[t * K + j] - mx);
                s += wv[j];
            }
            float inv = 1.f / (s + 1e-10f) * (1.f / 3.f);
#pragma unroll
            for (int j = 0; j < K; ++j) anormS[t * K + j] = wv[j] * inv;
        }
        __syncthreads();

        if (w < 3) {
#pragma unroll
            for (int nt = 0; nt < 4; ++nt)
#pragma unroll
                for (int rg = 0; rg < 4; ++rg) {
                    int row = w * 16 + quad * 4 + rg;
                    float a = (row < NB) ? anormS[row] : 0.f;
                    float v = (acc2[nt][rg] + b2mS[nt * 16 + m16]) * a;
                    msgW[row][nt * 16 + m16] = (_Float16)v;
                }
        }
        __syncthreads();

        for (int d = t; d < CB * F; d += 256) {
            int cr = d >> 6, o = d & 63;
            float s = 0.f;
#pragma unroll
            for (int j = 0; j < K; ++j) s += (float)msgW[cr * K + j][o];
            outacc[d] += s;
        }
        __syncthreads();
    }

    for (int d = t; d < CB * F; d += 256)
        out[(size_t)blockIdx.x * (CB * F) + d] = outacc[d];
}

// ---------------------------------------------------------------------------
// Fallback fp32 pool (round-4 proven)
// ---------------------------------------------------------------------------
__global__ __launch_bounds__(256)
void pool_kernel(const float* __restrict__ x,
                 const float* __restrict__ cgW1, const float* __restrict__ cgb1,
                 const float* __restrict__ cgW2, const float* __restrict__ cgb2,
                 const float* __restrict__ cmW1, const float* __restrict__ cmb1,
                 const float* __restrict__ cmW2, const float* __restrict__ cmb2,
                 const float* __restrict__ cpw, const float* __restrict__ wts,
                 float* __restrict__ out)
{
    __shared__ float xs[K * F];
    __shared__ float hmS[K][HID];
    __shared__ float msgS[K][F];
    __shared__ float outacc[F];
    __shared__ float b1g[HID], b1m[HID], w2g[HID];
    __shared__ float b2mS[F];
    __shared__ float gpart[K][2];
    __shared__ float gate_s[K];
    __shared__ float anorm[K];
    __shared__ float wn[K], wpow[K];

    const int c = blockIdx.x;
    const int t = threadIdx.x;
    const int wave = t >> 6, lane = t & 63;

    for (int d = t; d < K * F; d += 256) xs[d] = x[c * K * F + d];
    if (t < F) outacc[t] = 0.f;
    if (t < K) wn[t] = wts[c * K + t];
    __syncthreads();

    for (int h = 0; h < NH; ++h) {
        if (t < HID) {
            b1g[t] = cgb1[(size_t)h * HID + t];
            b1m[t] = cmb1[(size_t)h * HID + t];
            w2g[t] = cgW2[(size_t)h * HID + t];
        }
        if (t < F) b2mS[t] = cmb2[(size_t)h * F + t];
        if (t < K) wpow[t] = powf(wn[t], cpw[h]);
        __syncthreads();

        {
            const int grp = t >> 7;
            const int up  = t & 127;
            const float* Wb = (grp == 0 ? cgW1 : cmW1) + (size_t)h * F * HID;
            const float2* W2p = (const float2*)Wb;
            float acc[K][2];
#pragma unroll
            for (int i = 0; i < K; ++i) { acc[i][0] = 0.f; acc[i][1] = 0.f; }
            for (int k = 0; k < F; ++k) {
                float2 wv = W2p[k * (HID / 2) + up];
#pragma unroll
                for (int i = 0; i < K; ++i) {
                    float xv = xs[i * F + k];
                    acc[i][0] += xv * wv.x;
                    acc[i][1] += xv * wv.y;
                }
            }
            if (grp == 0) {
#pragma unroll
                for (int i = 0; i < K; ++i) {
                    float h0 = lrelu(acc[i][0] + b1g[2 * up]);
                    float h1 = lrelu(acc[i][1] + b1g[2 * up + 1]);
                    float part = h0 * w2g[2 * up] + h1 * w2g[2 * up + 1];
#pragma unroll
                    for (int s = 32; s; s >>= 1) part += __shfl_xor(part, s);
                    if (lane == 0) gpart[i][wave & 1] = part;
                }
            } else {
#pragma unroll
                for (int i = 0; i < K; ++i) {
                    hmS[i][2 * up]     = lrelu(acc[i][0] + b1m[2 * up]);
                    hmS[i][2 * up + 1] = lrelu(acc[i][1] + b1m[2 * up + 1]);
                }
            }
        }
        __syncthreads();
        if (t < K) gate_s[t] = cgb2[h] + gpart[t][0] + gpart[t][1];

        {
            const float2* W232 = (const float2*)(cmW2 + (size_t)h * HID * F);
            if (t < K * (F / 2)) {
                int i  = t >> 5;
                int op = t & 31;
                float a0 = b2mS[2 * op], a1 = b2mS[2 * op + 1];
#pragma unroll 8
                for (int u = 0; u < HID; ++u) {
                    float2 wv = W232[u * (F / 2) + op];
                    float hv = hmS[i][u];
                    a0 += hv * wv.x;
                    a1 += hv * wv.y;
                }
                msgS[i][2 * op]     = a0;
                msgS[i][2 * op + 1] = a1;
            }
        }
        __syncthreads();

        if (t == 0) {
            float mx = -1e30f;
#pragma unroll
            for (int i = 0; i < K; ++i) mx = fmaxf(mx, gate_s[i]);
            float wv[K], s = 0.f;
#pragma unroll
            for (int i = 0; i < K; ++i) {
                wv[i] = wpow[i] * expf(gate_s[i] - mx);
                s += wv[i];
            }
            float inv = 1.f / (s + 1e-10f);
#pragma unroll
            for (int i = 0; i < K; ++i) anorm[i] = wv[i] * inv;
        }
        __syncthreads();

        if (t < F) {
            float s = 0.f;
#pragma unroll
            for (int i = 0; i < K; ++i) s += anorm[i] * msgS[i][t];
            outacc[t] += s * (1.f / 3.f);
        }
        __syncthreads();
    }

    if (t < F) out[(size_t)c * F + t] = outacc[t];
}

// ---------------------------------------------------------------------------
extern "C" void kernel_launch(void* const* d_in, const int* in_sizes, int n_in,
                              void* d_out, int out_size, void* d_ws, size_t ws_size,
                              hipStream_t stream)
{
    const float* wts  = (const float*)d_in[0];
    const float* fea  = (const float*)d_in[1];
    const float* embW = (const float*)d_in[6];
    const float* embB = (const float*)d_in[7];
    const float* gW1  = (const float*)d_in[8];
    const float* gb1  = (const float*)d_in[9];
    const float* gW2  = (const float*)d_in[10];
    const float* gb2  = (const float*)d_in[11];
    const float* mW1  = (const float*)d_in[12];
    const float* mb1  = (const float*)d_in[13];
    const float* mW2  = (const float*)d_in[14];
    const float* mb2  = (const float*)d_in[15];
    const float* gpw  = (const float*)d_in[16];
    const float* cgW1 = (const float*)d_in[17];
    const float* cgb1 = (const float*)d_in[18];
    const float* cgW2 = (const float*)d_in[19];
    const float* cgb2 = (const float*)d_in[20];
    const float* cmW1 = (const float*)d_in[21];
    const float* cmb1 = (const float*)d_in[22];
    const float* cmW2 = (const float*)d_in[23];
    const float* cmb2 = (const float*)d_in[24];
    const float* cpw  = (const float*)d_in[25];

    const int N = in_sizes[0];   // 50000
    const int C = N / K;         // 10000
    const int layer_blocks = (C + 11) / 12;   // 834 (tail block guarded)

    float* x = (float*)d_ws;                       // [N,F] fp32, 12.8 MB
    const size_t xbytes = (size_t)N * F * 4;
    const size_t need = xbytes + (size_t)WALL_ELEMS * 2;

    // fp16 gate-W2 lives in the tail of d_out (scratch until pool overwrites it;
    // all layer_wave launches complete before pool runs). 4608 B, 16-aligned.
    _Float16* wgh = (_Float16*)((char*)d_out + ((size_t)out_size - WG_ELEMS * 2 - 15
                                                & ~(size_t)15));

    embed_kernel<<<N, 64, 0, stream>>>(fea, embW, embB, wts, x);
    prep_wg<<<(WG_ELEMS + 255) / 256, 256, 0, stream>>>(gW2, wgh);

    if (ws_size >= need) {
        // ---- fast path ----
        _Float16* Wall  = (_Float16*)((char*)d_ws + xbytes);
        _Float16* W1sw  = Wall;
        _Float16* W2sw  = Wall + W1SW_ELEMS;
        _Float16* cW1sw = Wall + W1SW_ELEMS + W2SW_ELEMS;
        _Float16* cW2sw = Wall + W1SW_ELEMS + W2SW_ELEMS + CW1_ELEMS;

        prep_all<<<(WALL_ELEMS + 255) / 256, 256, 0, stream>>>(
            gW1, mW1, mW2, cgW1, cmW1, cmW2, Wall);
        for (int l = 0; l < NL; ++l)
            layer_wave<<<layer_blocks, 256, 0, stream>>>(x, W1sw, W2sw,
                                                         gb1, gb2, mb1, mb2, wgh, gpw, wts,
                                                         l, l * NH, N);
        pool_mfma<<<C / CB, 256, 0, stream>>>(x, cW1sw, cW2sw,
                                              cgb1, cgb2, cmb1, cmb2, cgW2, cpw, wts,
                                              (float*)d_out);
    } else {
        // ---- fallback: per-layer prep into d_out scratch ----
        _Float16* W1sw = (_Float16*)d_out;
        _Float16* W2sw = (_Float16*)((char*)d_out + 393216);
        for (int l = 0; l < NL; ++l) {
            prep_layer<<<(W1L_ELEMS + W2L_ELEMS) / 256, 256, 0, stream>>>(
                gW1, mW1, mW2, W1sw, W2sw, l);
            layer_wave<<<layer_blocks, 256, 0, stream>>>(x, W1sw, W2sw,
                                                         gb1, gb2, mb1, mb2, wgh, gpw, wts,
                                                         l, 0, N);
        }
        pool_kernel<<<C, 256, 0, stream>>>(x, cgW1, cgb1, cgW2, cgb2,
                                           cmW1, cmb1, cmW2, cmb2, cpw, wts,
                                           (float*)d_out);
    }
}

// Round 2
// 973.795 us; speedup vs baseline: 1.3246x; 1.3246x over previous
//
#include <hip/hip_runtime.h>
#include <hip/hip_bf16.h>

#define K 5
#define F 64
#define EMBD 200
#define HID 256
#define NH 3
#define NL 3
#define CB 8            // crystals per block for POOL kernels
#define NB (CB * K)     // 40 nodes per pool block

// layer kernel: 4 waves x 3 crystals = 12 crystals / block
#define CW 3            // crystals per wave
#define NWN (CW * K)    // 15 nodes per wave
#define EWE (CW * K * K) // 75 edges per wave
#define ET 5            // edge tiles of 16

typedef _Float16 half8 __attribute__((ext_vector_type(8)));
typedef float f32x4 __attribute__((ext_vector_type(4)));

__device__ __forceinline__ float lrelu(float v) { return v >= 0.f ? v : 0.01f * v; }

__device__ __forceinline__ half8 lrelu8(half8 t) {
    half8 z = 0;
    half8 p = __builtin_elementwise_max(t, z);
    half8 n = __builtin_elementwise_min(t, z);
    return p + n * (_Float16)0.01f;
}

// ---- swizzled-weight element counts (fp16) ----
#define W1SW_ELEMS 589824    // 9 lh * 2 net * 2 half * 4 chunk * 4 nt * 2 ks * 64 * 8
#define W2SW_ELEMS 147456    // 9 lh * 8 ks2 * 4 nt * 64 * 8
#define CW1_ELEMS   98304    // 3 h * 2 net * 4 chunk * 4 nt * 2 ks * 64 * 8
#define CW2_ELEMS   49152    // 3 h * 8 ks2 * 4 nt * 64 * 8
#define WALL_ELEMS (W1SW_ELEMS + W2SW_ELEMS + CW1_ELEMS + CW2_ELEMS)  // 884736

// per-layer (fallback) sizes
#define W1L_ELEMS 196608
#define W2L_ELEMS 49152

// ---------------------------------------------------------------------------
// Fast path: swizzle ALL weights (layers + pool) fp32 -> fp16 B-frag order.
// ---------------------------------------------------------------------------
__global__ __launch_bounds__(256)
void prep_all(const float* __restrict__ gW1, const float* __restrict__ mW1,
              const float* __restrict__ mW2,
              const float* __restrict__ cgW1, const float* __restrict__ cmW1,
              const float* __restrict__ cmW2,
              _Float16* __restrict__ Wall)
{
    int tid = blockIdx.x * 256 + threadIdx.x;
    if (tid >= WALL_ELEMS) return;
    float v;
    if (tid < W1SW_ELEMS) {
        int j = tid & 7, lane = (tid >> 3) & 63;
        int r1 = tid >> 9;                       // [lh][net][half][chunk][nt][ks]
        int ks = r1 & 1, nt = (r1 >> 1) & 3, chunk = (r1 >> 3) & 3;
        int half = (r1 >> 5) & 1, net = (r1 >> 6) & 1, lh = r1 >> 7;   // 0..8
        int q = lane >> 4, n16 = lane & 15;
        const float* src = net ? mW1 : gW1;
        v = src[((size_t)lh * 128 + half * 64 + ks * 32 + q * 8 + j) * 256
                + chunk * 64 + nt * 16 + n16];
    } else if (tid < W1SW_ELEMS + W2SW_ELEMS) {
        int t2 = tid - W1SW_ELEMS;
        int j = t2 & 7, lane = (t2 >> 3) & 63;
        int r1 = t2 >> 9;                        // [lh][ks2][nt]
        int nt = r1 & 3, ks2 = (r1 >> 2) & 7, lh = r1 >> 5;            // 0..8
        int q = lane >> 4, n16 = lane & 15;
        v = mW2[((size_t)lh * 256 + ks2 * 32 + q * 8 + j) * 64 + nt * 16 + n16];
    } else if (tid < W1SW_ELEMS + W2SW_ELEMS + CW1_ELEMS) {
        int t2 = tid - (W1SW_ELEMS + W2SW_ELEMS);
        int j = t2 & 7, lane = (t2 >> 3) & 63;
        int r1 = t2 >> 9;                        // [h][net][chunk][nt][ks]
        int ks = r1 & 1, nt = (r1 >> 1) & 3, chunk = (r1 >> 3) & 3;
        int net = (r1 >> 5) & 1, h = r1 >> 6;                          // 0..2
        int q = lane >> 4, n16 = lane & 15;
        const float* src = net ? cmW1 : cgW1;
        v = src[((size_t)h * 64 + ks * 32 + q * 8 + j) * 256
                + chunk * 64 + nt * 16 + n16];
    } else {
        int t2 = tid - (W1SW_ELEMS + W2SW_ELEMS + CW1_ELEMS);
        int j = t2 & 7, lane = (t2 >> 3) & 63;
        int r1 = t2 >> 9;                        // [h][ks2][nt]
        int nt = r1 & 3, ks2 = (r1 >> 2) & 7, h = r1 >> 5;             // 0..2
        int q = lane >> 4, n16 = lane & 15;
        v = cmW2[((size_t)h * 256 + ks2 * 32 + q * 8 + j) * 64 + nt * 16 + n16];
    }
    Wall[tid] = (_Float16)v;
}

// ---------------------------------------------------------------------------
// Fallback: per-layer prep into d_out scratch (round-4 proven).
// ---------------------------------------------------------------------------
__global__ __launch_bounds__(256)
void prep_layer(const float* __restrict__ gW1, const float* __restrict__ mW1,
                const float* __restrict__ mW2,
                _Float16* __restrict__ W1sw, _Float16* __restrict__ W2sw, int l)
{
    int tid = blockIdx.x * 256 + threadIdx.x;
    if (tid < W1L_ELEMS) {
        int j = tid & 7, lane = (tid >> 3) & 63;
        int r1 = tid >> 9;
        int ks = r1 & 1, nt = (r1 >> 1) & 3, chunk = (r1 >> 3) & 3;
        int half = (r1 >> 5) & 1, net = (r1 >> 6) & 1, hh = r1 >> 7;
        int q = lane >> 4, n16 = lane & 15;
        const float* src = net ? mW1 : gW1;
        float v = src[((size_t)(l * NH + hh) * 128 + half * 64 + ks * 32 + q * 8 + j) * 256
                      + chunk * 64 + nt * 16 + n16];
        W1sw[tid] = (_Float16)v;
    } else {
        int t2 = tid - W1L_ELEMS;
        if (t2 < W2L_ELEMS) {
            int j = t2 & 7, lane = (t2 >> 3) & 63;
            int r1 = t2 >> 9;
            int nt = r1 & 3, ks2 = (r1 >> 2) & 7, hh = r1 >> 5;
            int q = lane >> 4, n16 = lane & 15;
            float v = mW2[((size_t)(l * NH + hh) * 256 + ks2 * 32 + q * 8 + j) * 64
                          + nt * 16 + n16];
            W2sw[t2] = (_Float16)v;
        }
    }
}

// ---------------------------------------------------------------------------
// Embedding — round 9: 16 nodes / 256-thread block (was 1 node / 64 threads).
// W traffic amortized 16x per block; fea tile staged in LDS; thread (nl,o)
// computes 4 output cols {o, o+16, o+32, o+48} for node nl. Col 63 = weights.
// ---------------------------------------------------------------------------
#define ENB 16   // nodes per embed block

__global__ __launch_bounds__(256)
void embed_kernel(const float* __restrict__ fea, const float* __restrict__ W,
                  const float* __restrict__ b, const float* __restrict__ wts,
                  float* __restrict__ x, int Ntot)
{
    __shared__ float fs[ENB * EMBD];
    const int t = threadIdx.x;
    const int node0 = blockIdx.x * ENB;
    int nvalid = Ntot - node0;
    if (nvalid > ENB) nvalid = ENB;
    if (nvalid <= 0) return;
    const int lim = nvalid * EMBD;
    for (int d = t; d < lim; d += 256) fs[d] = fea[(size_t)node0 * EMBD + d];
    __syncthreads();

    const int nl = t >> 4;          // local node 0..15
    const int o  = t & 15;          // output column group
    if (nl >= nvalid) return;
    const int n = node0 + nl;

    float acc[4];
#pragma unroll
    for (int k2 = 0; k2 < 4; ++k2) {
        int oc = o + 16 * k2;
        acc[k2] = (oc < F - 1) ? b[oc] : wts[n];
    }
    const float* fsr = fs + nl * EMBD;
#pragma unroll 4
    for (int e = 0; e < EMBD; ++e) {
        float xv = fsr[e];                       // quad-broadcast LDS read
        const float* wr = W + (size_t)e * (F - 1);
#pragma unroll
        for (int k2 = 0; k2 < 4; ++k2) {
            int oc = o + 16 * k2;
            if (oc < F - 1) acc[k2] += xv * wr[oc];
        }
    }
#pragma unroll
    for (int k2 = 0; k2 < 4; ++k2)
        x[(size_t)n * F + o + 16 * k2] = acc[k2];
}

// ---------------------------------------------------------------------------
// One graph layer — barrier-free, 4 independent waves / block, each wave owns
// 3 crystals (15 nodes, 75 edges). GEMM2 B-frags hoisted (loaded once per
// chunk, reused by 5 edge-tiles). Wave-private LDS slice 12288 B.
// __launch_bounds__(256) only: round 7's (256,3) pin capped VGPRs at 84 and
// spilled the MFMA accumulators to scratch (147 MB/dispatch HBM writes).
// Round 8 (gate-MFMA + bias-fold into C-init) REGRESSED 235->348 us: removed
// VALU was free latency-filler; bias-in-C-init serialized stage-1 on global
// loads and the scheduler collapsed to a low-ILP schedule (VGPR 184->140).
// Round 9: reverted verbatim to the round-7/round-0 proven 235 us version.
// ---------------------------------------------------------------------------
#define WAVE_LDS 12288   // bytes per wave slice

__global__ __launch_bounds__(256)
void layer_wave(float* __restrict__ x,
                const _Float16* __restrict__ W1sw,
                const _Float16* __restrict__ W2sw,
                const float* __restrict__ gb1, const float* __restrict__ gb2v,
                const float* __restrict__ mb1, const float* __restrict__ mb2,
                const float* __restrict__ gW2, const float* __restrict__ gpw,
                const float* __restrict__ wts, int l, int lhw0, int Ntot)
{
    __shared__ __align__(16) char smem[4 * WAVE_LDS];

    const int t = threadIdx.x, w = t >> 6, lane = t & 63;
    const int q = lane >> 4, m16 = lane & 15;

    char* wb = smem + w * WAVE_LDS;
    _Float16 (*PQ)[16][72] = (_Float16 (*)[16][72])wb;   // [4][16][72] = 9216 B
    _Float16 (*msgL)[72]   = (_Float16 (*)[72])wb;       // [80][72] = 11520 B (aliases PQ)
    float* gateS  = (float*)(wb + 11520);                // [80]
    float* anormS = (float*)(wb + 11840);                // [80]
    float* wpowS  = (float*)(wb + 12160);                // [16]

    const int nw0 = (blockIdx.x * 12 + w * CW) * K;      // first node of this wave
    const int vn  = (Ntot - nw0 < NWN) ? (Ntot - nw0) : NWN;  // valid nodes (may be <=0)

    // ---- A-fragments of x (head/half-invariant), fp16, loaded once ----
    half8 A[2];
    {
        int arow = nw0 + m16;
        if (arow > Ntot - 1) arow = Ntot - 1;            // clamp pad rows (finite junk)
        if (arow < 0) arow = 0;
        const float* xr = x + (size_t)arow * F;
#pragma unroll
        for (int ks = 0; ks < 2; ++ks) {
            float4 f0 = *(const float4*)(xr + ks * 32 + q * 8);
            float4 f1 = *(const float4*)(xr + ks * 32 + q * 8 + 4);
            half8 a;
            a[0] = (_Float16)f0.x; a[1] = (_Float16)f0.y;
            a[2] = (_Float16)f0.z; a[3] = (_Float16)f0.w;
            a[4] = (_Float16)f1.x; a[5] = (_Float16)f1.y;
            a[6] = (_Float16)f1.z; a[7] = (_Float16)f1.w;
            A[ks] = a;
        }
    }

    // ---- per-lane edge -> local node rows (75 valid edges in 5 tiles of 16) ----
    int iR[ET], jR[ET];
#pragma unroll
    for (int et = 0; et < ET; ++et) {
        int e = et * 16 + m16;
        if (e < EWE) {
            int cl = e / 25, rm = e % 25;
            iR[et] = cl * K + rm / K;
            jR[et] = cl * K + rm % K;
        } else { iR[et] = 15; jR[et] = 15; }             // pad row (clamped x, finite)
    }

    float oacc[NWN];
#pragma unroll
    for (int n = 0; n < NWN; ++n) oacc[n] = 0.f;

    for (int h = 0; h < NH; ++h) {
        const int lh = l * NH + h, lhw = lhw0 + h;

        if (lane < NWN) {
            int wi = nw0 + lane;
            if (wi > Ntot - 1) wi = Ntot - 1;
            if (wi < 0) wi = 0;
            wpowS[lane] = powf(wts[wi], gpw[lh]);
        }
        if (lane >= NWN && lane < NWN + 5) anormS[EWE + (lane - NWN)] = 0.f;  // pad slots 75..79

        f32x4 acc2[ET][4];
#pragma unroll
        for (int et = 0; et < ET; ++et)
#pragma unroll
            for (int nt = 0; nt < 4; ++nt) acc2[et][nt] = (f32x4){0.f, 0.f, 0.f, 0.f};
        float gacc[ET] = {0.f, 0.f, 0.f, 0.f, 0.f};

        for (int c = 0; c < 4; ++c) {
            // ---- GEMM2 B-frags for this chunk: issue early, reuse for 5 et ----
            half8 B2[8];
            {
                const _Float16* W2b = W2sw + ((size_t)lhw * 8 + c * 2) * 2048;
#pragma unroll
                for (int f = 0; f < 8; ++f)
                    B2[f] = *(const half8*)(W2b + ((size_t)f * 64 + lane) * 8);
            }

            // ---- stage-1: all 4 net-halves (0:Pg 1:Qg 2:Pm 3:Qm) ----
#pragma unroll
            for (int hf = 0; hf < 4; ++hf) {
                f32x4 accS[4];
#pragma unroll
                for (int nt = 0; nt < 4; ++nt) accS[nt] = (f32x4){0.f, 0.f, 0.f, 0.f};
                const _Float16* Wb = W1sw + ((size_t)lhw * 4 + hf) * 16384 + c * 4096;
#pragma unroll
                for (int nt = 0; nt < 4; ++nt)
#pragma unroll
                    for (int ks = 0; ks < 2; ++ks) {
                        half8 B = *(const half8*)(Wb + ((nt * 2 + ks) * 64 + lane) * 8);
                        accS[nt] = __builtin_amdgcn_mfma_f32_16x16x32_f16(
                            A[ks], B, accS[nt], 0, 0, 0);
                    }
#pragma unroll
                for (int nt = 0; nt < 4; ++nt)
#pragma unroll
                    for (int rg = 0; rg < 4; ++rg)
                        PQ[hf][q * 4 + rg][nt * 16 + m16] = (_Float16)accS[nt][rg];
            }

            // ---- per-chunk bias slices (global, L1-hot) ----
            half8 bg8[2], bm8[2];
            float wg[2][8];
#pragma unroll
            for (int ks = 0; ks < 2; ++ks) {
                const int ub = c * 64 + ks * 32 + q * 8;
                float4 g0 = *(const float4*)(gb1 + (size_t)lh * HID + ub);
                float4 g1 = *(const float4*)(gb1 + (size_t)lh * HID + ub + 4);
                float4 m0 = *(const float4*)(mb1 + (size_t)lh * HID + ub);
                float4 m1 = *(const float4*)(mb1 + (size_t)lh * HID + ub + 4);
                float4 w0 = *(const float4*)(gW2 + (size_t)lh * HID + ub);
                float4 w1 = *(const float4*)(gW2 + (size_t)lh * HID + ub + 4);
                half8 bg, bm;
                bg[0]=(_Float16)g0.x; bg[1]=(_Float16)g0.y; bg[2]=(_Float16)g0.z; bg[3]=(_Float16)g0.w;
                bg[4]=(_Float16)g1.x; bg[5]=(_Float16)g1.y; bg[6]=(_Float16)g1.z; bg[7]=(_Float16)g1.w;
                bm[0]=(_Float16)m0.x; bm[1]=(_Float16)m0.y; bm[2]=(_Float16)m0.z; bm[3]=(_Float16)m0.w;
                bm[4]=(_Float16)m1.x; bm[5]=(_Float16)m1.y; bm[6]=(_Float16)m1.z; bm[7]=(_Float16)m1.w;
                bg8[ks] = bg; bm8[ks] = bm;
                wg[ks][0]=w0.x; wg[ks][1]=w0.y; wg[ks][2]=w0.z; wg[ks][3]=w0.w;
                wg[ks][4]=w1.x; wg[ks][5]=w1.y; wg[ks][6]=w1.z; wg[ks][7]=w1.w;
            }

            // ---- consume: gate partial + hm A-frags + GEMM2 (B2 reused) ----
#pragma unroll
            for (int et = 0; et < ET; ++et) {
                half8 af[2];
#pragma unroll
                for (int ks = 0; ks < 2; ++ks) {
                    const int ub = ks * 32 + q * 8;
                    half8 pg = *(const half8*)&PQ[0][iR[et]][ub];
                    half8 qg = *(const half8*)&PQ[1][jR[et]][ub];
                    half8 pm = *(const half8*)&PQ[2][iR[et]][ub];
                    half8 qm = *(const half8*)&PQ[3][jR[et]][ub];
                    half8 tg = lrelu8(pg + qg + bg8[ks]);
#pragma unroll
                    for (int jj = 0; jj < 8; ++jj)
                        gacc[et] += (float)tg[jj] * wg[ks][jj];
                    af[ks] = lrelu8(pm + qm + bm8[ks]);
                }
#pragma unroll
                for (int nt = 0; nt < 4; ++nt)
#pragma unroll
                    for (int ks = 0; ks < 2; ++ks)
                        acc2[et][nt] = __builtin_amdgcn_mfma_f32_16x16x32_f16(
                            af[ks], B2[ks * 4 + nt], acc2[et][nt], 0, 0, 0);
            }
        }

        // ---- gate reduce across quads (k-slices) ----
        const float gb2s = gb2v[lh];
#pragma unroll
        for (int et = 0; et < ET; ++et) {
            float g = gacc[et];
            g += __shfl_xor(g, 16);
            g += __shfl_xor(g, 32);
            if (q == 0) gateS[et * 16 + m16] = g + gb2s;
        }

        // ---- segment softmax: lane n (0..14) handles local node n (5 edges) ----
        if (lane < NWN) {
            const int cl5 = (lane / K) * K;
            float gg[K], mx = -1e30f;
#pragma unroll
            for (int jj = 0; jj < K; ++jj) {
                gg[jj] = gateS[lane * K + jj];
                mx = fmaxf(mx, gg[jj]);
            }
            float s = 0.f, wv[K];
#pragma unroll
            for (int jj = 0; jj < K; ++jj) {
                wv[jj] = wpowS[cl5 + jj] * expf(gg[jj] - mx);
                s += wv[jj];
            }
            float inv = 1.f / (s + 1e-10f) * (1.f / 3.f);  // fold head mean
#pragma unroll
            for (int jj = 0; jj < K; ++jj) anormS[lane * K + jj] = wv[jj] * inv;
        }

        // ---- weighted msg -> msgL (PQ region dead) ----
        float b2v[4];
#pragma unroll
        for (int nt = 0; nt < 4; ++nt) b2v[nt] = mb2[(size_t)lh * F + nt * 16 + m16];
#pragma unroll
        for (int et = 0; et < ET; ++et) {
            f32x4 an = *(const f32x4*)&anormS[et * 16 + q * 4];
#pragma unroll
            for (int nt = 0; nt < 4; ++nt)
#pragma unroll
                for (int rg = 0; rg < 4; ++rg) {
                    float v = (acc2[et][nt][rg] + b2v[nt]) * an[rg];
                    msgL[et * 16 + q * 4 + rg][nt * 16 + m16] = (_Float16)v;
                }
        }

        // ---- aggregate: lane = output col, 15 nodes x 5 edges ----
#pragma unroll
        for (int n = 0; n < NWN; ++n) {
            float s = 0.f;
#pragma unroll
            for (int jj = 0; jj < K; ++jj) s += (float)msgL[n * K + jj][lane];
            oacc[n] += s;
        }
    }

    // ---- residual + write back (own valid rows only) ----
#pragma unroll
    for (int n = 0; n < NWN; ++n) {
        if (n < vn) {
            size_t idx = (size_t)(nw0 + n) * F + lane;
            x[idx] = oacc[n] + x[idx];
        }
    }
}

// ---------------------------------------------------------------------------
// MFMA pool (round-5 proven)
// ---------------------------------------------------------------------------
__global__ __launch_bounds__(256)
void pool_mfma(const float* __restrict__ x,
               const _Float16* __restrict__ cW1sw,
               const _Float16* __restrict__ cW2sw,
               const float* __restrict__ cgb1, const float* __restrict__ cgb2v,
               const float* __restrict__ cmb1, const float* __restrict__ cmb2,
               const float* __restrict__ cgW2, const float* __restrict__ cpw,
               const float* __restrict__ wts, float* __restrict__ out)
{
    __shared__ __align__(16) _Float16 xh[48][72];
    __shared__ __align__(16) char PQraw[2 * 48 * 72 * 2];
    __shared__ float outacc[CB * F];
    __shared__ float b1gS[HID], b1mS[HID], w2gS[HID], b2mS[F];
    __shared__ float gateS[48], anormS[48], wpowS[48];

    _Float16 (*P)[48][72] = (_Float16 (*)[48][72])PQraw;
    _Float16 (*msgW)[72]  = (_Float16 (*)[72])PQraw;

    const int t = threadIdx.x, w = t >> 6, lane = t & 63;
    const int quad = lane >> 4, m16 = lane & 15;
    const int node0 = blockIdx.x * NB;

    for (int d = t; d < 48 * 64; d += 256) {
        int r = d >> 6, cc = d & 63;
        float v = (r < NB) ? x[(size_t)(node0 + r) * F + cc] : 0.f;
        xh[r][cc] = (_Float16)v;
    }
    for (int d = t; d < CB * F; d += 256) outacc[d] = 0.f;
    __syncthreads();

    half8 A[3][2];
#pragma unroll
    for (int Mt = 0; Mt < 3; ++Mt)
#pragma unroll
        for (int ks = 0; ks < 2; ++ks)
            A[Mt][ks] = *(const half8*)&xh[Mt * 16 + m16][ks * 32 + quad * 8];

    const int net = w >> 1, ntp = w & 1;

    for (int h = 0; h < NH; ++h) {
        if (t < HID) {
            b1gS[t] = cgb1[(size_t)h * HID + t];
            b1mS[t] = cmb1[(size_t)h * HID + t];
            w2gS[t] = cgW2[(size_t)h * HID + t];
        }
        if (t < F)  b2mS[t] = cmb2[(size_t)h * F + t];
        if (t < NB) wpowS[t] = powf(wts[node0 + t], cpw[h]);
        const float gb2s = cgb2v[h];

        f32x4 acc2[4];
#pragma unroll
        for (int nt = 0; nt < 4; ++nt) acc2[nt] = (f32x4){0.f, 0.f, 0.f, 0.f};
        float gacc = 0.f;

        for (int chunk = 0; chunk < 4; ++chunk) {
            {
                f32x4 accS[3][2];
#pragma unroll
                for (int Mt = 0; Mt < 3; ++Mt)
#pragma unroll
                    for (int n2 = 0; n2 < 2; ++n2) accS[Mt][n2] = (f32x4){0.f, 0.f, 0.f, 0.f};
                const _Float16* Wb = cW1sw + ((size_t)(h * 2 + net) * 4 + chunk) * 4096;
#pragma unroll
                for (int n2 = 0; n2 < 2; ++n2) {
                    int nt = ntp * 2 + n2;
#pragma unroll
                    for (int ks = 0; ks < 2; ++ks) {
                        half8 B = *(const half8*)(Wb + ((nt * 2 + ks) * 64 + lane) * 8);
#pragma unroll
                        for (int Mt = 0; Mt < 3; ++Mt)
                            accS[Mt][n2] = __builtin_amdgcn_mfma_f32_16x16x32_f16(
                                A[Mt][ks], B, accS[Mt][n2], 0, 0, 0);
                    }
                }
#pragma unroll
                for (int Mt = 0; Mt < 3; ++Mt)
#pragma unroll
                    for (int n2 = 0; n2 < 2; ++n2)
#pragma unroll
                        for (int rg = 0; rg < 4; ++rg)
                            P[net][Mt * 16 + quad * 4 + rg][(ntp * 2 + n2) * 16 + m16] =
                                (_Float16)accS[Mt][n2][rg];
            }
            __syncthreads();

            if (w < 3) {
                half8 af[2];
#pragma unroll
                for (int ks = 0; ks < 2; ++ks) {
                    const int ub = ks * 32 + quad * 8;
                    half8 pg = *(const half8*)&P[0][w * 16 + m16][ub];
                    half8 pm = *(const half8*)&P[1][w * 16 + m16][ub];
#pragma unroll
                    for (int j = 0; j < 8; ++j) {
                        int u = chunk * 64 + ub + j;
                        float gh = lrelu((float)pg[j] + b1gS[u]);
                        gacc += gh * w2gS[u];
                        float hv = lrelu((float)pm[j] + b1mS[u]);
                        af[ks][j] = (_Float16)hv;
                    }
                }
                const _Float16* W2b = cW2sw + (size_t)h * 16384 + chunk * 4096;
#pragma unroll
                for (int nt = 0; nt < 4; ++nt)
#pragma unroll
                    for (int ks = 0; ks < 2; ++ks) {
                        half8 B = *(const half8*)(W2b + ((size_t)(ks * 4 + nt) * 64 + lane) * 8);
                        acc2[nt] = __builtin_amdgcn_mfma_f32_16x16x32_f16(
                            af[ks], B, acc2[nt], 0, 0, 0);
                    }
            }
            __syncthreads();
        }

        if (w < 3) {
            float g = gacc;
            g += __shfl_xor(g, 16);
            g += __shfl_xor(g, 32);
            if (quad == 0) gateS[w * 16 + m16] = g + gb2s;
        }
        __syncthreads();

        if (t < CB) {
            float mx = -1e30f;
#pragma unroll
            for (int j = 0; j < K; ++j) mx = fmaxf(mx, gateS[t * K + j]);
            float s = 0.f, wv[K];
#pragma unroll
            for (int j = 0; j < K; ++j) {
                wv[j] = wpowS[t * K + j] * expf(gateS[t * K + j] - mx);
                s += wv[j];
            }
            float inv = 1.f / (s + 1e-10f) * (1.f / 3.f);
#pragma unroll
            for (int j = 0; j < K; ++j) anormS[t * K + j] = wv[j] * inv;
        }
        __syncthreads();

        if (w < 3) {
#pragma unroll
            for (int nt = 0; nt < 4; ++nt)
#pragma unroll
                for (int rg = 0; rg < 4; ++rg) {
                    int row = w * 16 + quad * 4 + rg;
                    float a = (row < NB) ? anormS[row] : 0.f;
                    float v = (acc2[nt][rg] + b2mS[nt * 16 + m16]) * a;
                    msgW[row][nt * 16 + m16] = (_Float16)v;
                }
        }
        __syncthreads();

        for (int d = t; d < CB * F; d += 256) {
            int cr = d >> 6, o = d & 63;
            float s = 0.f;
#pragma unroll
            for (int j = 0; j < K; ++j) s += (float)msgW[cr * K + j][o];
            outacc[d] += s;
        }
        __syncthreads();
    }

    for (int d = t; d < CB * F; d += 256)
        out[(size_t)blockIdx.x * (CB * F) + d] = outacc[d];
}

// ---------------------------------------------------------------------------
// Fallback fp32 pool (round-4 proven)
// ---------------------------------------------------------------------------
__global__ __launch_bounds__(256)
void pool_kernel(const float* __restrict__ x,
                 const float* __restrict__ cgW1, const float* __restrict__ cgb1,
                 const float* __restrict__ cgW2, const float* __restrict__ cgb2,
                 const float* __restrict__ cmW1, const float* __restrict__ cmb1,
                 const float* __restrict__ cmW2, const float* __restrict__ cmb2,
                 const float* __restrict__ cpw, const float* __restrict__ wts,
                 float* __restrict__ out)
{
    __shared__ float xs[K * F];
    __shared__ float hmS[K][HID];
    __shared__ float msgS[K][F];
    __shared__ float outacc[F];
    __shared__ float b1g[HID], b1m[HID], w2g[HID];
    __shared__ float b2mS[F];
    __shared__ float gpart[K][2];
    __shared__ float gate_s[K];
    __shared__ float anorm[K];
    __shared__ float wn[K], wpow[K];

    const int c = blockIdx.x;
    const int t = threadIdx.x;
    const int wave = t >> 6, lane = t & 63;

    for (int d = t; d < K * F; d += 256) xs[d] = x[c * K * F + d];
    if (t < F) outacc[t] = 0.f;
    if (t < K) wn[t] = wts[c * K + t];
    __syncthreads();

    for (int h = 0; h < NH; ++h) {
        if (t < HID) {
            b1g[t] = cgb1[(size_t)h * HID + t];
            b1m[t] = cmb1[(size_t)h * HID + t];
            w2g[t] = cgW2[(size_t)h * HID + t];
        }
        if (t < F) b2mS[t] = cmb2[(size_t)h * F + t];
        if (t < K) wpow[t] = powf(wn[t], cpw[h]);
        __syncthreads();

        {
            const int grp = t >> 7;
            const int up  = t & 127;
            const float* Wb = (grp == 0 ? cgW1 : cmW1) + (size_t)h * F * HID;
            const float2* W2p = (const float2*)Wb;
            float acc[K][2];
#pragma unroll
            for (int i = 0; i < K; ++i) { acc[i][0] = 0.f; acc[i][1] = 0.f; }
            for (int k = 0; k < F; ++k) {
                float2 wv = W2p[k * (HID / 2) + up];
#pragma unroll
                for (int i = 0; i < K; ++i) {
                    float xv = xs[i * F + k];
                    acc[i][0] += xv * wv.x;
                    acc[i][1] += xv * wv.y;
                }
            }
            if (grp == 0) {
#pragma unroll
                for (int i = 0; i < K; ++i) {
                    float h0 = lrelu(acc[i][0] + b1g[2 * up]);
                    float h1 = lrelu(acc[i][1] + b1g[2 * up + 1]);
                    float part = h0 * w2g[2 * up] + h1 * w2g[2 * up + 1];
#pragma unroll
                    for (int s = 32; s; s >>= 1) part += __shfl_xor(part, s);
                    if (lane == 0) gpart[i][wave & 1] = part;
                }
            } else {
#pragma unroll
                for (int i = 0; i < K; ++i) {
                    hmS[i][2 * up]     = lrelu(acc[i][0] + b1m[2 * up]);
                    hmS[i][2 * up + 1] = lrelu(acc[i][1] + b1m[2 * up + 1]);
                }
            }
        }
        __syncthreads();
        if (t < K) gate_s[t] = cgb2[h] + gpart[t][0] + gpart[t][1];

        {
            const float2* W232 = (const float2*)(cmW2 + (size_t)h * HID * F);
            if (t < K * (F / 2)) {
                int i  = t >> 5;
                int op = t & 31;
                float a0 = b2mS[2 * op], a1 = b2mS[2 * op + 1];
#pragma unroll 8
                for (int u = 0; u < HID; ++u) {
                    float2 wv = W232[u * (F / 2) + op];
                    float hv = hmS[i][u];
                    a0 += hv * wv.x;
                    a1 += hv * wv.y;
                }
                msgS[i][2 * op]     = a0;
                msgS[i][2 * op + 1] = a1;
            }
        }
        __syncthreads();

        if (t == 0) {
            float mx = -1e30f;
#pragma unroll
            for (int i = 0; i < K; ++i) mx = fmaxf(mx, gate_s[i]);
            float wv[K], s = 0.f;
#pragma unroll
            for (int i = 0; i < K; ++i) {
                wv[i] = wpow[i] * expf(gate_s[i] - mx);
                s += wv[i];
            }
            float inv = 1.f / (s + 1e-10f);
#pragma unroll
            for (int i = 0; i < K; ++i) anorm[i] = wv[i] * inv;
        }
        __syncthreads();

        if (t < F) {
            float s = 0.f;
#pragma unroll
            for (int i = 0; i < K; ++i) s += anorm[i] * msgS[i][t];
            outacc[t] += s * (1.f / 3.f);
        }
        __syncthreads();
    }

    if (t < F) out[(size_t)c * F + t] = outacc[t];
}

// ---------------------------------------------------------------------------
extern "C" void kernel_launch(void* const* d_in, const int* in_sizes, int n_in,
                              void* d_out, int out_size, void* d_ws, size_t ws_size,
                              hipStream_t stream)
{
    const float* wts  = (const float*)d_in[0];
    const float* fea  = (const float*)d_in[1];
    const float* embW = (const float*)d_in[6];
    const float* embB = (const float*)d_in[7];
    const float* gW1  = (const float*)d_in[8];
    const float* gb1  = (const float*)d_in[9];
    const float* gW2  = (const float*)d_in[10];
    const float* gb2  = (const float*)d_in[11];
    const float* mW1  = (const float*)d_in[12];
    const float* mb1  = (const float*)d_in[13];
    const float* mW2  = (const float*)d_in[14];
    const float* mb2  = (const float*)d_in[15];
    const float* gpw  = (const float*)d_in[16];
    const float* cgW1 = (const float*)d_in[17];
    const float* cgb1 = (const float*)d_in[18];
    const float* cgW2 = (const float*)d_in[19];
    const float* cgb2 = (const float*)d_in[20];
    const float* cmW1 = (const float*)d_in[21];
    const float* cmb1 = (const float*)d_in[22];
    const float* cmW2 = (const float*)d_in[23];
    const float* cmb2 = (const float*)d_in[24];
    const float* cpw  = (const float*)d_in[25];

    const int N = in_sizes[0];   // 50000
    const int C = N / K;         // 10000
    const int layer_blocks = (C + 11) / 12;   // 834 (tail block guarded)

    float* x = (float*)d_ws;                       // [N,F] fp32, 12.8 MB
    const size_t xbytes = (size_t)N * F * 4;
    const size_t need = xbytes + (size_t)WALL_ELEMS * 2;

    embed_kernel<<<(N + ENB - 1) / ENB, 256, 0, stream>>>(fea, embW, embB, wts, x, N);

    if (ws_size >= need) {
        // ---- fast path ----
        _Float16* Wall  = (_Float16*)((char*)d_ws + xbytes);
        _Float16* W1sw  = Wall;
        _Float16* W2sw  = Wall + W1SW_ELEMS;
        _Float16* cW1sw = Wall + W1SW_ELEMS + W2SW_ELEMS;
        _Float16* cW2sw = Wall + W1SW_ELEMS + W2SW_ELEMS + CW1_ELEMS;

        prep_all<<<(WALL_ELEMS + 255) / 256, 256, 0, stream>>>(
            gW1, mW1, mW2, cgW1, cmW1, cmW2, Wall);
        for (int l = 0; l < NL; ++l)
            layer_wave<<<layer_blocks, 256, 0, stream>>>(x, W1sw, W2sw,
                                                         gb1, gb2, mb1, mb2, gW2, gpw, wts,
                                                         l, l * NH, N);
        pool_mfma<<<C / CB, 256, 0, stream>>>(x, cW1sw, cW2sw,
                                              cgb1, cgb2, cmb1, cmb2, cgW2, cpw, wts,
                                              (float*)d_out);
    } else {
        // ---- fallback: per-layer prep into d_out scratch ----
        _Float16* W1sw = (_Float16*)d_out;
        _Float16* W2sw = (_Float16*)((char*)d_out + 393216);
        for (int l = 0; l < NL; ++l) {
            prep_layer<<<(W1L_ELEMS + W2L_ELEMS) / 256, 256, 0, stream>>>(
                gW1, mW1, mW2, W1sw, W2sw, l);
            layer_wave<<<layer_blocks, 256, 0, stream>>>(x, W1sw, W2sw,
                                                         gb1, gb2, mb1, mb2, gW2, gpw, wts,
                                                         l, 0, N);
        }
        pool_kernel<<<C, 256, 0, stream>>>(x, cgW1, cgb1, cgW2, cgb2,
                                           cmW1, cmb1, cmW2, cmb2, cpw, wts,
                                           (float*)d_out);
    }
}

// Round 3
// 883.482 us; speedup vs baseline: 1.4600x; 1.1022x over previous
//
#include <hip/hip_runtime.h>
#include <hip/hip_bf16.h>

#define K 5
#define F 64
#define EMBD 200
#define HID 256
#define NH 3
#define NL 3
#define CB 8            // crystals per block for POOL kernels
#define NB (CB * K)     // 40 nodes per pool block

// layer kernel: 4 waves x 3 crystals = 12 crystals / block
#define CW 3            // crystals per wave
#define NWN (CW * K)    // 15 nodes per wave
#define EWE (CW * K * K) // 75 edges per wave
#define ET 5            // edge tiles of 16

typedef _Float16 half8 __attribute__((ext_vector_type(8)));
typedef float f32x4 __attribute__((ext_vector_type(4)));

__device__ __forceinline__ float lrelu(float v) { return v >= 0.f ? v : 0.01f * v; }

__device__ __forceinline__ half8 lrelu8(half8 t) {
    half8 z = 0;
    half8 p = __builtin_elementwise_max(t, z);
    half8 n = __builtin_elementwise_min(t, z);
    return p + n * (_Float16)0.01f;
}

// ---- swizzled-weight element counts (fp16) ----
#define W1SW_ELEMS 589824    // 9 lh * 2 net * 2 half * 4 chunk * 4 nt * 2 ks * 64 * 8
#define W2SW_ELEMS 147456    // 9 lh * 8 ks2 * 4 nt * 64 * 8
#define CW1_ELEMS   98304    // 3 h * 2 net * 4 chunk * 4 nt * 2 ks * 64 * 8
#define CW2_ELEMS   49152    // 3 h * 8 ks2 * 4 nt * 64 * 8
#define WALL_ELEMS (W1SW_ELEMS + W2SW_ELEMS + CW1_ELEMS + CW2_ELEMS)  // 884736

// per-layer (fallback) sizes
#define W1L_ELEMS 196608
#define W2L_ELEMS 49152

// ---------------------------------------------------------------------------
// Fast path: swizzle ALL weights (layers + pool) fp32 -> fp16 B-frag order.
// ---------------------------------------------------------------------------
__global__ __launch_bounds__(256)
void prep_all(const float* __restrict__ gW1, const float* __restrict__ mW1,
              const float* __restrict__ mW2,
              const float* __restrict__ cgW1, const float* __restrict__ cmW1,
              const float* __restrict__ cmW2,
              _Float16* __restrict__ Wall)
{
    int tid = blockIdx.x * 256 + threadIdx.x;
    if (tid >= WALL_ELEMS) return;
    float v;
    if (tid < W1SW_ELEMS) {
        int j = tid & 7, lane = (tid >> 3) & 63;
        int r1 = tid >> 9;                       // [lh][net][half][chunk][nt][ks]
        int ks = r1 & 1, nt = (r1 >> 1) & 3, chunk = (r1 >> 3) & 3;
        int half = (r1 >> 5) & 1, net = (r1 >> 6) & 1, lh = r1 >> 7;   // 0..8
        int q = lane >> 4, n16 = lane & 15;
        const float* src = net ? mW1 : gW1;
        v = src[((size_t)lh * 128 + half * 64 + ks * 32 + q * 8 + j) * 256
                + chunk * 64 + nt * 16 + n16];
    } else if (tid < W1SW_ELEMS + W2SW_ELEMS) {
        int t2 = tid - W1SW_ELEMS;
        int j = t2 & 7, lane = (t2 >> 3) & 63;
        int r1 = t2 >> 9;                        // [lh][ks2][nt]
        int nt = r1 & 3, ks2 = (r1 >> 2) & 7, lh = r1 >> 5;            // 0..8
        int q = lane >> 4, n16 = lane & 15;
        v = mW2[((size_t)lh * 256 + ks2 * 32 + q * 8 + j) * 64 + nt * 16 + n16];
    } else if (tid < W1SW_ELEMS + W2SW_ELEMS + CW1_ELEMS) {
        int t2 = tid - (W1SW_ELEMS + W2SW_ELEMS);
        int j = t2 & 7, lane = (t2 >> 3) & 63;
        int r1 = t2 >> 9;                        // [h][net][chunk][nt][ks]
        int ks = r1 & 1, nt = (r1 >> 1) & 3, chunk = (r1 >> 3) & 3;
        int net = (r1 >> 5) & 1, h = r1 >> 6;                          // 0..2
        int q = lane >> 4, n16 = lane & 15;
        const float* src = net ? cmW1 : cgW1;
        v = src[((size_t)h * 64 + ks * 32 + q * 8 + j) * 256
                + chunk * 64 + nt * 16 + n16];
    } else {
        int t2 = tid - (W1SW_ELEMS + W2SW_ELEMS + CW1_ELEMS);
        int j = t2 & 7, lane = (t2 >> 3) & 63;
        int r1 = t2 >> 9;                        // [h][ks2][nt]
        int nt = r1 & 3, ks2 = (r1 >> 2) & 7, h = r1 >> 5;             // 0..2
        int q = lane >> 4, n16 = lane & 15;
        v = cmW2[((size_t)h * 256 + ks2 * 32 + q * 8 + j) * 64 + nt * 16 + n16];
    }
    Wall[tid] = (_Float16)v;
}

// ---------------------------------------------------------------------------
// Fallback: per-layer prep into d_out scratch (round-4 proven).
// ---------------------------------------------------------------------------
__global__ __launch_bounds__(256)
void prep_layer(const float* __restrict__ gW1, const float* __restrict__ mW1,
                const float* __restrict__ mW2,
                _Float16* __restrict__ W1sw, _Float16* __restrict__ W2sw, int l)
{
    int tid = blockIdx.x * 256 + threadIdx.x;
    if (tid < W1L_ELEMS) {
        int j = tid & 7, lane = (tid >> 3) & 63;
        int r1 = tid >> 9;
        int ks = r1 & 1, nt = (r1 >> 1) & 3, chunk = (r1 >> 3) & 3;
        int half = (r1 >> 5) & 1, net = (r1 >> 6) & 1, hh = r1 >> 7;
        int q = lane >> 4, n16 = lane & 15;
        const float* src = net ? mW1 : gW1;
        float v = src[((size_t)(l * NH + hh) * 128 + half * 64 + ks * 32 + q * 8 + j) * 256
                      + chunk * 64 + nt * 16 + n16];
        W1sw[tid] = (_Float16)v;
    } else {
        int t2 = tid - W1L_ELEMS;
        if (t2 < W2L_ELEMS) {
            int j = t2 & 7, lane = (t2 >> 3) & 63;
            int r1 = t2 >> 9;
            int nt = r1 & 3, ks2 = (r1 >> 2) & 7, hh = r1 >> 5;
            int q = lane >> 4, n16 = lane & 15;
            float v = mW2[((size_t)(l * NH + hh) * 256 + ks2 * 32 + q * 8 + j) * 64
                          + nt * 16 + n16];
            W2sw[t2] = (_Float16)v;
        }
    }
}

// ---------------------------------------------------------------------------
// Embedding — 16 nodes / 256-thread block; fea tile staged in LDS; thread
// (nl,o) computes 4 output cols {o, o+16, o+32, o+48} for node nl.
// ---------------------------------------------------------------------------
#define ENB 16   // nodes per embed block

__global__ __launch_bounds__(256)
void embed_kernel(const float* __restrict__ fea, const float* __restrict__ W,
                  const float* __restrict__ b, const float* __restrict__ wts,
                  float* __restrict__ x, int Ntot)
{
    __shared__ float fs[ENB * EMBD];
    const int t = threadIdx.x;
    const int node0 = blockIdx.x * ENB;
    int nvalid = Ntot - node0;
    if (nvalid > ENB) nvalid = ENB;
    if (nvalid <= 0) return;
    const int lim = nvalid * EMBD;
    for (int d = t; d < lim; d += 256) fs[d] = fea[(size_t)node0 * EMBD + d];
    __syncthreads();

    const int nl = t >> 4;          // local node 0..15
    const int o  = t & 15;          // output column group
    if (nl >= nvalid) return;
    const int n = node0 + nl;

    float acc[4];
#pragma unroll
    for (int k2 = 0; k2 < 4; ++k2) {
        int oc = o + 16 * k2;
        acc[k2] = (oc < F - 1) ? b[oc] : wts[n];
    }
    const float* fsr = fs + nl * EMBD;
#pragma unroll 4
    for (int e = 0; e < EMBD; ++e) {
        float xv = fsr[e];                       // quad-broadcast LDS read
        const float* wr = W + (size_t)e * (F - 1);
#pragma unroll
        for (int k2 = 0; k2 < 4; ++k2) {
            int oc = o + 16 * k2;
            if (oc < F - 1) acc[k2] += xv * wr[oc];
        }
    }
#pragma unroll
    for (int k2 = 0; k2 < 4; ++k2)
        x[(size_t)n * F + o + 16 * k2] = acc[k2];
}

// ---------------------------------------------------------------------------
// One graph layer — barrier-free, 4 independent waves / block, each wave owns
// 3 crystals (15 nodes, 75 edges). GEMM2 B-frags hoisted (loaded once per
// chunk, reused by 5 edge-tiles). Wave-private LDS slice 12288 B.
//
// Round 10: __launch_bounds__(256, 2). Occupancy analysis: measured ~9.3%
// occupancy == 1 block/CU resident (4 waves). VGPR_Count=184 is arch-only;
// with ~96 MFMA accumulator regs the unified total is ~280 > 256 -> 1
// wave/SIMD, zero latency hiding. (256,2) caps total at 256/wave (gentle:
// ~24 regs of rematerialization), targeting 2 blocks/CU. Round-7's (256,3)
// demanded <=170 and spilled catastrophically — this is the soft version.
// Spill tripwire: WRITE_SIZE per dispatch must stay ~12.5 MB.
// ---------------------------------------------------------------------------
#define WAVE_LDS 12288   // bytes per wave slice

__global__ __launch_bounds__(256, 2)
void layer_wave(float* __restrict__ x,
                const _Float16* __restrict__ W1sw,
                const _Float16* __restrict__ W2sw,
                const float* __restrict__ gb1, const float* __restrict__ gb2v,
                const float* __restrict__ mb1, const float* __restrict__ mb2,
                const float* __restrict__ gW2, const float* __restrict__ gpw,
                const float* __restrict__ wts, int l, int lhw0, int Ntot)
{
    __shared__ __align__(16) char smem[4 * WAVE_LDS];

    const int t = threadIdx.x, w = t >> 6, lane = t & 63;
    const int q = lane >> 4, m16 = lane & 15;

    char* wb = smem + w * WAVE_LDS;
    _Float16 (*PQ)[16][72] = (_Float16 (*)[16][72])wb;   // [4][16][72] = 9216 B
    _Float16 (*msgL)[72]   = (_Float16 (*)[72])wb;       // [80][72] = 11520 B (aliases PQ)
    float* gateS  = (float*)(wb + 11520);                // [80]
    float* anormS = (float*)(wb + 11840);                // [80]
    float* wpowS  = (float*)(wb + 12160);                // [16]

    const int nw0 = (blockIdx.x * 12 + w * CW) * K;      // first node of this wave
    const int vn  = (Ntot - nw0 < NWN) ? (Ntot - nw0) : NWN;  // valid nodes (may be <=0)

    // ---- A-fragments of x (head/half-invariant), fp16, loaded once ----
    half8 A[2];
    {
        int arow = nw0 + m16;
        if (arow > Ntot - 1) arow = Ntot - 1;            // clamp pad rows (finite junk)
        if (arow < 0) arow = 0;
        const float* xr = x + (size_t)arow * F;
#pragma unroll
        for (int ks = 0; ks < 2; ++ks) {
            float4 f0 = *(const float4*)(xr + ks * 32 + q * 8);
            float4 f1 = *(const float4*)(xr + ks * 32 + q * 8 + 4);
            half8 a;
            a[0] = (_Float16)f0.x; a[1] = (_Float16)f0.y;
            a[2] = (_Float16)f0.z; a[3] = (_Float16)f0.w;
            a[4] = (_Float16)f1.x; a[5] = (_Float16)f1.y;
            a[6] = (_Float16)f1.z; a[7] = (_Float16)f1.w;
            A[ks] = a;
        }
    }

    // ---- per-lane edge -> local node rows (75 valid edges in 5 tiles of 16) ----
    int iR[ET], jR[ET];
#pragma unroll
    for (int et = 0; et < ET; ++et) {
        int e = et * 16 + m16;
        if (e < EWE) {
            int cl = e / 25, rm = e % 25;
            iR[et] = cl * K + rm / K;
            jR[et] = cl * K + rm % K;
        } else { iR[et] = 15; jR[et] = 15; }             // pad row (clamped x, finite)
    }

    float oacc[NWN];
#pragma unroll
    for (int n = 0; n < NWN; ++n) oacc[n] = 0.f;

    for (int h = 0; h < NH; ++h) {
        const int lh = l * NH + h, lhw = lhw0 + h;

        if (lane < NWN) {
            int wi = nw0 + lane;
            if (wi > Ntot - 1) wi = Ntot - 1;
            if (wi < 0) wi = 0;
            wpowS[lane] = powf(wts[wi], gpw[lh]);
        }
        if (lane >= NWN && lane < NWN + 5) anormS[EWE + (lane - NWN)] = 0.f;  // pad slots 75..79

        f32x4 acc2[ET][4];
#pragma unroll
        for (int et = 0; et < ET; ++et)
#pragma unroll
            for (int nt = 0; nt < 4; ++nt) acc2[et][nt] = (f32x4){0.f, 0.f, 0.f, 0.f};
        float gacc[ET] = {0.f, 0.f, 0.f, 0.f, 0.f};

        for (int c = 0; c < 4; ++c) {
            // ---- GEMM2 B-frags for this chunk: issue early, reuse for 5 et ----
            half8 B2[8];
            {
                const _Float16* W2b = W2sw + ((size_t)lhw * 8 + c * 2) * 2048;
#pragma unroll
                for (int f = 0; f < 8; ++f)
                    B2[f] = *(const half8*)(W2b + ((size_t)f * 64 + lane) * 8);
            }

            // ---- stage-1: all 4 net-halves (0:Pg 1:Qg 2:Pm 3:Qm) ----
#pragma unroll
            for (int hf = 0; hf < 4; ++hf) {
                f32x4 accS[4];
#pragma unroll
                for (int nt = 0; nt < 4; ++nt) accS[nt] = (f32x4){0.f, 0.f, 0.f, 0.f};
                const _Float16* Wb = W1sw + ((size_t)lhw * 4 + hf) * 16384 + c * 4096;
#pragma unroll
                for (int nt = 0; nt < 4; ++nt)
#pragma unroll
                    for (int ks = 0; ks < 2; ++ks) {
                        half8 B = *(const half8*)(Wb + ((nt * 2 + ks) * 64 + lane) * 8);
                        accS[nt] = __builtin_amdgcn_mfma_f32_16x16x32_f16(
                            A[ks], B, accS[nt], 0, 0, 0);
                    }
#pragma unroll
                for (int nt = 0; nt < 4; ++nt)
#pragma unroll
                    for (int rg = 0; rg < 4; ++rg)
                        PQ[hf][q * 4 + rg][nt * 16 + m16] = (_Float16)accS[nt][rg];
            }

            // ---- per-chunk bias slices (global, L1-hot) ----
            half8 bg8[2], bm8[2];
            float wg[2][8];
#pragma unroll
            for (int ks = 0; ks < 2; ++ks) {
                const int ub = c * 64 + ks * 32 + q * 8;
                float4 g0 = *(const float4*)(gb1 + (size_t)lh * HID + ub);
                float4 g1 = *(const float4*)(gb1 + (size_t)lh * HID + ub + 4);
                float4 m0 = *(const float4*)(mb1 + (size_t)lh * HID + ub);
                float4 m1 = *(const float4*)(mb1 + (size_t)lh * HID + ub + 4);
                float4 w0 = *(const float4*)(gW2 + (size_t)lh * HID + ub);
                float4 w1 = *(const float4*)(gW2 + (size_t)lh * HID + ub + 4);
                half8 bg, bm;
                bg[0]=(_Float16)g0.x; bg[1]=(_Float16)g0.y; bg[2]=(_Float16)g0.z; bg[3]=(_Float16)g0.w;
                bg[4]=(_Float16)g1.x; bg[5]=(_Float16)g1.y; bg[6]=(_Float16)g1.z; bg[7]=(_Float16)g1.w;
                bm[0]=(_Float16)m0.x; bm[1]=(_Float16)m0.y; bm[2]=(_Float16)m0.z; bm[3]=(_Float16)m0.w;
                bm[4]=(_Float16)m1.x; bm[5]=(_Float16)m1.y; bm[6]=(_Float16)m1.z; bm[7]=(_Float16)m1.w;
                bg8[ks] = bg; bm8[ks] = bm;
                wg[ks][0]=w0.x; wg[ks][1]=w0.y; wg[ks][2]=w0.z; wg[ks][3]=w0.w;
                wg[ks][4]=w1.x; wg[ks][5]=w1.y; wg[ks][6]=w1.z; wg[ks][7]=w1.w;
            }

            // ---- consume: gate partial + hm A-frags + GEMM2 (B2 reused) ----
#pragma unroll
            for (int et = 0; et < ET; ++et) {
                half8 af[2];
#pragma unroll
                for (int ks = 0; ks < 2; ++ks) {
                    const int ub = ks * 32 + q * 8;
                    half8 pg = *(const half8*)&PQ[0][iR[et]][ub];
                    half8 qg = *(const half8*)&PQ[1][jR[et]][ub];
                    half8 pm = *(const half8*)&PQ[2][iR[et]][ub];
                    half8 qm = *(const half8*)&PQ[3][jR[et]][ub];
                    half8 tg = lrelu8(pg + qg + bg8[ks]);
#pragma unroll
                    for (int jj = 0; jj < 8; ++jj)
                        gacc[et] += (float)tg[jj] * wg[ks][jj];
                    af[ks] = lrelu8(pm + qm + bm8[ks]);
                }
#pragma unroll
                for (int nt = 0; nt < 4; ++nt)
#pragma unroll
                    for (int ks = 0; ks < 2; ++ks)
                        acc2[et][nt] = __builtin_amdgcn_mfma_f32_16x16x32_f16(
                            af[ks], B2[ks * 4 + nt], acc2[et][nt], 0, 0, 0);
            }
        }

        // ---- gate reduce across quads (k-slices) ----
        const float gb2s = gb2v[lh];
#pragma unroll
        for (int et = 0; et < ET; ++et) {
            float g = gacc[et];
            g += __shfl_xor(g, 16);
            g += __shfl_xor(g, 32);
            if (q == 0) gateS[et * 16 + m16] = g + gb2s;
        }

        // ---- segment softmax: lane n (0..14) handles local node n (5 edges) ----
        if (lane < NWN) {
            const int cl5 = (lane / K) * K;
            float gg[K], mx = -1e30f;
#pragma unroll
            for (int jj = 0; jj < K; ++jj) {
                gg[jj] = gateS[lane * K + jj];
                mx = fmaxf(mx, gg[jj]);
            }
            float s = 0.f, wv[K];
#pragma unroll
            for (int jj = 0; jj < K; ++jj) {
                wv[jj] = wpowS[cl5 + jj] * expf(gg[jj] - mx);
                s += wv[jj];
            }
            float inv = 1.f / (s + 1e-10f) * (1.f / 3.f);  // fold head mean
#pragma unroll
            for (int jj = 0; jj < K; ++jj) anormS[lane * K + jj] = wv[jj] * inv;
        }

        // ---- weighted msg -> msgL (PQ region dead) ----
        float b2v[4];
#pragma unroll
        for (int nt = 0; nt < 4; ++nt) b2v[nt] = mb2[(size_t)lh * F + nt * 16 + m16];
#pragma unroll
        for (int et = 0; et < ET; ++et) {
            f32x4 an = *(const f32x4*)&anormS[et * 16 + q * 4];
#pragma unroll
            for (int nt = 0; nt < 4; ++nt)
#pragma unroll
                for (int rg = 0; rg < 4; ++rg) {
                    float v = (acc2[et][nt][rg] + b2v[nt]) * an[rg];
                    msgL[et * 16 + q * 4 + rg][nt * 16 + m16] = (_Float16)v;
                }
        }

        // ---- aggregate: lane = output col, 15 nodes x 5 edges ----
#pragma unroll
        for (int n = 0; n < NWN; ++n) {
            float s = 0.f;
#pragma unroll
            for (int jj = 0; jj < K; ++jj) s += (float)msgL[n * K + jj][lane];
            oacc[n] += s;
        }
    }

    // ---- residual + write back (own valid rows only) ----
#pragma unroll
    for (int n = 0; n < NWN; ++n) {
        if (n < vn) {
            size_t idx = (size_t)(nw0 + n) * F + lane;
            x[idx] = oacc[n] + x[idx];
        }
    }
}

// ---------------------------------------------------------------------------
// MFMA pool (round-5 proven)
// ---------------------------------------------------------------------------
__global__ __launch_bounds__(256)
void pool_mfma(const float* __restrict__ x,
               const _Float16* __restrict__ cW1sw,
               const _Float16* __restrict__ cW2sw,
               const float* __restrict__ cgb1, const float* __restrict__ cgb2v,
               const float* __restrict__ cmb1, const float* __restrict__ cmb2,
               const float* __restrict__ cgW2, const float* __restrict__ cpw,
               const float* __restrict__ wts, float* __restrict__ out)
{
    __shared__ __align__(16) _Float16 xh[48][72];
    __shared__ __align__(16) char PQraw[2 * 48 * 72 * 2];
    __shared__ float outacc[CB * F];
    __shared__ float b1gS[HID], b1mS[HID], w2gS[HID], b2mS[F];
    __shared__ float gateS[48], anormS[48], wpowS[48];

    _Float16 (*P)[48][72] = (_Float16 (*)[48][72])PQraw;
    _Float16 (*msgW)[72]  = (_Float16 (*)[72])PQraw;

    const int t = threadIdx.x, w = t >> 6, lane = t & 63;
    const int quad = lane >> 4, m16 = lane & 15;
    const int node0 = blockIdx.x * NB;

    for (int d = t; d < 48 * 64; d += 256) {
        int r = d >> 6, cc = d & 63;
        float v = (r < NB) ? x[(size_t)(node0 + r) * F + cc] : 0.f;
        xh[r][cc] = (_Float16)v;
    }
    for (int d = t; d < CB * F; d += 256) outacc[d] = 0.f;
    __syncthreads();

    half8 A[3][2];
#pragma unroll
    for (int Mt = 0; Mt < 3; ++Mt)
#pragma unroll
        for (int ks = 0; ks < 2; ++ks)
            A[Mt][ks] = *(const half8*)&xh[Mt * 16 + m16][ks * 32 + quad * 8];

    const int net = w >> 1, ntp = w & 1;

    for (int h = 0; h < NH; ++h) {
        if (t < HID) {
            b1gS[t] = cgb1[(size_t)h * HID + t];
            b1mS[t] = cmb1[(size_t)h * HID + t];
            w2gS[t] = cgW2[(size_t)h * HID + t];
        }
        if (t < F)  b2mS[t] = cmb2[(size_t)h * F + t];
        if (t < NB) wpowS[t] = powf(wts[node0 + t], cpw[h]);
        const float gb2s = cgb2v[h];

        f32x4 acc2[4];
#pragma unroll
        for (int nt = 0; nt < 4; ++nt) acc2[nt] = (f32x4){0.f, 0.f, 0.f, 0.f};
        float gacc = 0.f;

        for (int chunk = 0; chunk < 4; ++chunk) {
            {
                f32x4 accS[3][2];
#pragma unroll
                for (int Mt = 0; Mt < 3; ++Mt)
#pragma unroll
                    for (int n2 = 0; n2 < 2; ++n2) accS[Mt][n2] = (f32x4){0.f, 0.f, 0.f, 0.f};
                const _Float16* Wb = cW1sw + ((size_t)(h * 2 + net) * 4 + chunk) * 4096;
#pragma unroll
                for (int n2 = 0; n2 < 2; ++n2) {
                    int nt = ntp * 2 + n2;
#pragma unroll
                    for (int ks = 0; ks < 2; ++ks) {
                        half8 B = *(const half8*)(Wb + ((nt * 2 + ks) * 64 + lane) * 8);
#pragma unroll
                        for (int Mt = 0; Mt < 3; ++Mt)
                            accS[Mt][n2] = __builtin_amdgcn_mfma_f32_16x16x32_f16(
                                A[Mt][ks], B, accS[Mt][n2], 0, 0, 0);
                    }
                }
#pragma unroll
                for (int Mt = 0; Mt < 3; ++Mt)
#pragma unroll
                    for (int n2 = 0; n2 < 2; ++n2)
#pragma unroll
                        for (int rg = 0; rg < 4; ++rg)
                            P[net][Mt * 16 + quad * 4 + rg][(ntp * 2 + n2) * 16 + m16] =
                                (_Float16)accS[Mt][n2][rg];
            }
            __syncthreads();

            if (w < 3) {
                half8 af[2];
#pragma unroll
                for (int ks = 0; ks < 2; ++ks) {
                    const int ub = ks * 32 + quad * 8;
                    half8 pg = *(const half8*)&P[0][w * 16 + m16][ub];
                    half8 pm = *(const half8*)&P[1][w * 16 + m16][ub];
#pragma unroll
                    for (int j = 0; j < 8; ++j) {
                        int u = chunk * 64 + ub + j;
                        float gh = lrelu((float)pg[j] + b1gS[u]);
                        gacc += gh * w2gS[u];
                        float hv = lrelu((float)pm[j] + b1mS[u]);
                        af[ks][j] = (_Float16)hv;
                    }
                }
                const _Float16* W2b = cW2sw + (size_t)h * 16384 + chunk * 4096;
#pragma unroll
                for (int nt = 0; nt < 4; ++nt)
#pragma unroll
                    for (int ks = 0; ks < 2; ++ks) {
                        half8 B = *(const half8*)(W2b + ((size_t)(ks * 4 + nt) * 64 + lane) * 8);
                        acc2[nt] = __builtin_amdgcn_mfma_f32_16x16x32_f16(
                            af[ks], B, acc2[nt], 0, 0, 0);
                    }
            }
            __syncthreads();
        }

        if (w < 3) {
            float g = gacc;
            g += __shfl_xor(g, 16);
            g += __shfl_xor(g, 32);
            if (quad == 0) gateS[w * 16 + m16] = g + gb2s;
        }
        __syncthreads();

        if (t < CB) {
            float mx = -1e30f;
#pragma unroll
            for (int j = 0; j < K; ++j) mx = fmaxf(mx, gateS[t * K + j]);
            float s = 0.f, wv[K];
#pragma unroll
            for (int j = 0; j < K; ++j) {
                wv[j] = wpowS[t * K + j] * expf(gateS[t * K + j] - mx);
                s += wv[j];
            }
            float inv = 1.f / (s + 1e-10f) * (1.f / 3.f);
#pragma unroll
            for (int j = 0; j < K; ++j) anormS[t * K + j] = wv[j] * inv;
        }
        __syncthreads();

        if (w < 3) {
#pragma unroll
            for (int nt = 0; nt < 4; ++nt)
#pragma unroll
                for (int rg = 0; rg < 4; ++rg) {
                    int row = w * 16 + quad * 4 + rg;
                    float a = (row < NB) ? anormS[row] : 0.f;
                    float v = (acc2[nt][rg] + b2mS[nt * 16 + m16]) * a;
                    msgW[row][nt * 16 + m16] = (_Float16)v;
                }
        }
        __syncthreads();

        for (int d = t; d < CB * F; d += 256) {
            int cr = d >> 6, o = d & 63;
            float s = 0.f;
#pragma unroll
            for (int j = 0; j < K; ++j) s += (float)msgW[cr * K + j][o];
            outacc[d] += s;
        }
        __syncthreads();
    }

    for (int d = t; d < CB * F; d += 256)
        out[(size_t)blockIdx.x * (CB * F) + d] = outacc[d];
}

// ---------------------------------------------------------------------------
// Fallback fp32 pool (round-4 proven)
// ---------------------------------------------------------------------------
__global__ __launch_bounds__(256)
void pool_kernel(const float* __restrict__ x,
                 const float* __restrict__ cgW1, const float* __restrict__ cgb1,
                 const float* __restrict__ cgW2, const float* __restrict__ cgb2,
                 const float* __restrict__ cmW1, const float* __restrict__ cmb1,
                 const float* __restrict__ cmW2, const float* __restrict__ cmb2,
                 const float* __restrict__ cpw, const float* __restrict__ wts,
                 float* __restrict__ out)
{
    __shared__ float xs[K * F];
    __shared__ float hmS[K][HID];
    __shared__ float msgS[K][F];
    __shared__ float outacc[F];
    __shared__ float b1g[HID], b1m[HID], w2g[HID];
    __shared__ float b2mS[F];
    __shared__ float gpart[K][2];
    __shared__ float gate_s[K];
    __shared__ float anorm[K];
    __shared__ float wn[K], wpow[K];

    const int c = blockIdx.x;
    const int t = threadIdx.x;
    const int wave = t >> 6, lane = t & 63;

    for (int d = t; d < K * F; d += 256) xs[d] = x[c * K * F + d];
    if (t < F) outacc[t] = 0.f;
    if (t < K) wn[t] = wts[c * K + t];
    __syncthreads();

    for (int h = 0; h < NH; ++h) {
        if (t < HID) {
            b1g[t] = cgb1[(size_t)h * HID + t];
            b1m[t] = cmb1[(size_t)h * HID + t];
            w2g[t] = cgW2[(size_t)h * HID + t];
        }
        if (t < F) b2mS[t] = cmb2[(size_t)h * F + t];
        if (t < K) wpow[t] = powf(wn[t], cpw[h]);
        __syncthreads();

        {
            const int grp = t >> 7;
            const int up  = t & 127;
            const float* Wb = (grp == 0 ? cgW1 : cmW1) + (size_t)h * F * HID;
            const float2* W2p = (const float2*)Wb;
            float acc[K][2];
#pragma unroll
            for (int i = 0; i < K; ++i) { acc[i][0] = 0.f; acc[i][1] = 0.f; }
            for (int k = 0; k < F; ++k) {
                float2 wv = W2p[k * (HID / 2) + up];
#pragma unroll
                for (int i = 0; i < K; ++i) {
                    float xv = xs[i * F + k];
                    acc[i][0] += xv * wv.x;
                    acc[i][1] += xv * wv.y;
                }
            }
            if (grp == 0) {
#pragma unroll
                for (int i = 0; i < K; ++i) {
                    float h0 = lrelu(acc[i][0] + b1g[2 * up]);
                    float h1 = lrelu(acc[i][1] + b1g[2 * up + 1]);
                    float part = h0 * w2g[2 * up] + h1 * w2g[2 * up + 1];
#pragma unroll
                    for (int s = 32; s; s >>= 1) part += __shfl_xor(part, s);
                    if (lane == 0) gpart[i][wave & 1] = part;
                }
            } else {
#pragma unroll
                for (int i = 0; i < K; ++i) {
                    hmS[i][2 * up]     = lrelu(acc[i][0] + b1m[2 * up]);
                    hmS[i][2 * up + 1] = lrelu(acc[i][1] + b1m[2 * up + 1]);
                }
            }
        }
        __syncthreads();
        if (t < K) gate_s[t] = cgb2[h] + gpart[t][0] + gpart[t][1];

        {
            const float2* W232 = (const float2*)(cmW2 + (size_t)h * HID * F);
            if (t < K * (F / 2)) {
                int i  = t >> 5;
                int op = t & 31;
                float a0 = b2mS[2 * op], a1 = b2mS[2 * op + 1];
#pragma unroll 8
                for (int u = 0; u < HID; ++u) {
                    float2 wv = W232[u * (F / 2) + op];
                    float hv = hmS[i][u];
                    a0 += hv * wv.x;
                    a1 += hv * wv.y;
                }
                msgS[i][2 * op]     = a0;
                msgS[i][2 * op + 1] = a1;
            }
        }
        __syncthreads();

        if (t == 0) {
            float mx = -1e30f;
#pragma unroll
            for (int i = 0; i < K; ++i) mx = fmaxf(mx, gate_s[i]);
            float wv[K], s = 0.f;
#pragma unroll
            for (int i = 0; i < K; ++i) {
                wv[i] = wpow[i] * expf(gate_s[i] - mx);
                s += wv[i];
            }
            float inv = 1.f / (s + 1e-10f);
#pragma unroll
            for (int i = 0; i < K; ++i) anorm[i] = wv[i] * inv;
        }
        __syncthreads();

        if (t < F) {
            float s = 0.f;
#pragma unroll
            for (int i = 0; i < K; ++i) s += anorm[i] * msgS[i][t];
            outacc[t] += s * (1.f / 3.f);
        }
        __syncthreads();
    }

    if (t < F) out[(size_t)c * F + t] = outacc[t];
}

// ---------------------------------------------------------------------------
extern "C" void kernel_launch(void* const* d_in, const int* in_sizes, int n_in,
                              void* d_out, int out_size, void* d_ws, size_t ws_size,
                              hipStream_t stream)
{
    const float* wts  = (const float*)d_in[0];
    const float* fea  = (const float*)d_in[1];
    const float* embW = (const float*)d_in[6];
    const float* embB = (const float*)d_in[7];
    const float* gW1  = (const float*)d_in[8];
    const float* gb1  = (const float*)d_in[9];
    const float* gW2  = (const float*)d_in[10];
    const float* gb2  = (const float*)d_in[11];
    const float* mW1  = (const float*)d_in[12];
    const float* mb1  = (const float*)d_in[13];
    const float* mW2  = (const float*)d_in[14];
    const float* mb2  = (const float*)d_in[15];
    const float* gpw  = (const float*)d_in[16];
    const float* cgW1 = (const float*)d_in[17];
    const float* cgb1 = (const float*)d_in[18];
    const float* cgW2 = (const float*)d_in[19];
    const float* cgb2 = (const float*)d_in[20];
    const float* cmW1 = (const float*)d_in[21];
    const float* cmb1 = (const float*)d_in[22];
    const float* cmW2 = (const float*)d_in[23];
    const float* cmb2 = (const float*)d_in[24];
    const float* cpw  = (const float*)d_in[25];

    const int N = in_sizes[0];   // 50000
    const int C = N / K;         // 10000
    const int layer_blocks = (C + 11) / 12;   // 834 (tail block guarded)

    float* x = (float*)d_ws;                       // [N,F] fp32, 12.8 MB
    const size_t xbytes = (size_t)N * F * 4;
    const size_t need = xbytes + (size_t)WALL_ELEMS * 2;

    embed_kernel<<<(N + ENB - 1) / ENB, 256, 0, stream>>>(fea, embW, embB, wts, x, N);

    if (ws_size >= need) {
        // ---- fast path ----
        _Float16* Wall  = (_Float16*)((char*)d_ws + xbytes);
        _Float16* W1sw  = Wall;
        _Float16* W2sw  = Wall + W1SW_ELEMS;
        _Float16* cW1sw = Wall + W1SW_ELEMS + W2SW_ELEMS;
        _Float16* cW2sw = Wall + W1SW_ELEMS + W2SW_ELEMS + CW1_ELEMS;

        prep_all<<<(WALL_ELEMS + 255) / 256, 256, 0, stream>>>(
            gW1, mW1, mW2, cgW1, cmW1, cmW2, Wall);
        for (int l = 0; l < NL; ++l)
            layer_wave<<<layer_blocks, 256, 0, stream>>>(x, W1sw, W2sw,
                                                         gb1, gb2, mb1, mb2, gW2, gpw, wts,
                                                         l, l * NH, N);
        pool_mfma<<<C / CB, 256, 0, stream>>>(x, cW1sw, cW2sw,
                                              cgb1, cgb2, cmb1, cmb2, cgW2, cpw, wts,
                                              (float*)d_out);
    } else {
        // ---- fallback: per-layer prep into d_out scratch ----
        _Float16* W1sw = (_Float16*)d_out;
        _Float16* W2sw = (_Float16*)((char*)d_out + 393216);
        for (int l = 0; l < NL; ++l) {
            prep_layer<<<(W1L_ELEMS + W2L_ELEMS) / 256, 256, 0, stream>>>(
                gW1, mW1, mW2, W1sw, W2sw, l);
            layer_wave<<<layer_blocks, 256, 0, stream>>>(x, W1sw, W2sw,
                                                         gb1, gb2, mb1, mb2, gW2, gpw, wts,
                                                         l, 0, N);
        }
        pool_kernel<<<C, 256, 0, stream>>>(x, cgW1, cgb1, cgW2, cgb2,
                                           cmW1, cmb1, cmW2, cmb2, cpw, wts,
                                           (float*)d_out);
    }
}

// Round 5
// 859.200 us; speedup vs baseline: 1.5013x; 1.0283x over previous
//
#include <hip/hip_runtime.h>
#include <hip/hip_bf16.h>

#define K 5
#define F 64
#define EMBD 200
#define HID 256
#define NH 3
#define NL 3
#define CB 8            // crystals per block for POOL kernels
#define NB (CB * K)     // 40 nodes per pool block

// layer kernel: 4 waves x 3 crystals = 12 crystals / block
#define CW 3            // crystals per wave
#define NWN (CW * K)    // 15 nodes per wave
#define EWE (CW * K * K) // 75 edges per wave
#define ET 5            // edge tiles of 16

typedef _Float16 half8 __attribute__((ext_vector_type(8)));
typedef _Float16 h2 __attribute__((ext_vector_type(2)));
typedef _Float16 h4 __attribute__((ext_vector_type(4)));
typedef __fp16 fp16x2 __attribute__((ext_vector_type(2)));
typedef float f32x4 __attribute__((ext_vector_type(4)));

__device__ __forceinline__ float lrelu(float v) { return v >= 0.f ? v : 0.01f * v; }

// cvt_pkrtz returns __fp16x2; bitcast to _Float16x2 (same bits, distinct clang types)
__device__ __forceinline__ h2 cvt_pk(float a, float b) {
    union { fp16x2 f; h2 h; } u;
    u.f = __builtin_amdgcn_cvt_pkrtz(a, b);
    return u.h;
}

__device__ __forceinline__ half8 lrelu8(half8 t) {
    half8 z = 0;
    half8 p = __builtin_elementwise_max(t, z);
    half8 n = __builtin_elementwise_min(t, z);
    return p + n * (_Float16)0.01f;
}

// ---- swizzled-weight element counts (fp16) ----
#define W1SW_ELEMS 589824    // 9 lh * 2 net * 2 half * 4 chunk * 4 nt * 2 ks * 64 * 8
#define W2SW_ELEMS 147456    // 9 lh * 8 ks2 * 4 nt * 64 * 8
#define CW1_ELEMS   98304    // 3 h * 2 net * 4 chunk * 4 nt * 2 ks * 64 * 8
#define CW2_ELEMS   49152    // 3 h * 8 ks2 * 4 nt * 64 * 8
#define WALL_ELEMS (W1SW_ELEMS + W2SW_ELEMS + CW1_ELEMS + CW2_ELEMS)  // 884736

// per-layer (fallback) sizes
#define W1L_ELEMS 196608
#define W2L_ELEMS 49152

// ---------------------------------------------------------------------------
// Fast path: swizzle ALL weights (layers + pool) fp32 -> fp16 B-frag order.
// ---------------------------------------------------------------------------
__global__ __launch_bounds__(256)
void prep_all(const float* __restrict__ gW1, const float* __restrict__ mW1,
              const float* __restrict__ mW2,
              const float* __restrict__ cgW1, const float* __restrict__ cmW1,
              const float* __restrict__ cmW2,
              _Float16* __restrict__ Wall)
{
    int tid = blockIdx.x * 256 + threadIdx.x;
    if (tid >= WALL_ELEMS) return;
    float v;
    if (tid < W1SW_ELEMS) {
        int j = tid & 7, lane = (tid >> 3) & 63;
        int r1 = tid >> 9;                       // [lh][net][half][chunk][nt][ks]
        int ks = r1 & 1, nt = (r1 >> 1) & 3, chunk = (r1 >> 3) & 3;
        int half = (r1 >> 5) & 1, net = (r1 >> 6) & 1, lh = r1 >> 7;   // 0..8
        int q = lane >> 4, n16 = lane & 15;
        const float* src = net ? mW1 : gW1;
        v = src[((size_t)lh * 128 + half * 64 + ks * 32 + q * 8 + j) * 256
                + chunk * 64 + nt * 16 + n16];
    } else if (tid < W1SW_ELEMS + W2SW_ELEMS) {
        int t2 = tid - W1SW_ELEMS;
        int j = t2 & 7, lane = (t2 >> 3) & 63;
        int r1 = t2 >> 9;                        // [lh][ks2][nt]
        int nt = r1 & 3, ks2 = (r1 >> 2) & 7, lh = r1 >> 5;            // 0..8
        int q = lane >> 4, n16 = lane & 15;
        v = mW2[((size_t)lh * 256 + ks2 * 32 + q * 8 + j) * 64 + nt * 16 + n16];
    } else if (tid < W1SW_ELEMS + W2SW_ELEMS + CW1_ELEMS) {
        int t2 = tid - (W1SW_ELEMS + W2SW_ELEMS);
        int j = t2 & 7, lane = (t2 >> 3) & 63;
        int r1 = t2 >> 9;                        // [h][net][chunk][nt][ks]
        int ks = r1 & 1, nt = (r1 >> 1) & 3, chunk = (r1 >> 3) & 3;
        int net = (r1 >> 5) & 1, h = r1 >> 6;                          // 0..2
        int q = lane >> 4, n16 = lane & 15;
        const float* src = net ? cmW1 : cgW1;
        v = src[((size_t)h * 64 + ks * 32 + q * 8 + j) * 256
                + chunk * 64 + nt * 16 + n16];
    } else {
        int t2 = tid - (W1SW_ELEMS + W2SW_ELEMS + CW1_ELEMS);
        int j = t2 & 7, lane = (t2 >> 3) & 63;
        int r1 = t2 >> 9;                        // [h][ks2][nt]
        int nt = r1 & 3, ks2 = (r1 >> 2) & 7, h = r1 >> 5;             // 0..2
        int q = lane >> 4, n16 = lane & 15;
        v = cmW2[((size_t)h * 256 + ks2 * 32 + q * 8 + j) * 64 + nt * 16 + n16];
    }
    Wall[tid] = (_Float16)v;
}

// ---------------------------------------------------------------------------
// Fallback: per-layer prep into d_out scratch (round-4 proven).
// ---------------------------------------------------------------------------
__global__ __launch_bounds__(256)
void prep_layer(const float* __restrict__ gW1, const float* __restrict__ mW1,
                const float* __restrict__ mW2,
                _Float16* __restrict__ W1sw, _Float16* __restrict__ W2sw, int l)
{
    int tid = blockIdx.x * 256 + threadIdx.x;
    if (tid < W1L_ELEMS) {
        int j = tid & 7, lane = (tid >> 3) & 63;
        int r1 = tid >> 9;
        int ks = r1 & 1, nt = (r1 >> 1) & 3, chunk = (r1 >> 3) & 3;
        int half = (r1 >> 5) & 1, net = (r1 >> 6) & 1, hh = r1 >> 7;
        int q = lane >> 4, n16 = lane & 15;
        const float* src = net ? mW1 : gW1;
        float v = src[((size_t)(l * NH + hh) * 128 + half * 64 + ks * 32 + q * 8 + j) * 256
                      + chunk * 64 + nt * 16 + n16];
        W1sw[tid] = (_Float16)v;
    } else {
        int t2 = tid - W1L_ELEMS;
        if (t2 < W2L_ELEMS) {
            int j = t2 & 7, lane = (t2 >> 3) & 63;
            int r1 = t2 >> 9;
            int nt = r1 & 3, ks2 = (r1 >> 2) & 7, hh = r1 >> 5;
            int q = lane >> 4, n16 = lane & 15;
            float v = mW2[((size_t)(l * NH + hh) * 256 + ks2 * 32 + q * 8 + j) * 64
                          + nt * 16 + n16];
            W2sw[t2] = (_Float16)v;
        }
    }
}

// ---------------------------------------------------------------------------
// Embedding — 16 nodes / 256-thread block; fea tile staged in LDS; thread
// (nl,o) computes 4 output cols {o, o+16, o+32, o+48} for node nl.
// ---------------------------------------------------------------------------
#define ENB 16   // nodes per embed block

__global__ __launch_bounds__(256)
void embed_kernel(const float* __restrict__ fea, const float* __restrict__ W,
                  const float* __restrict__ b, const float* __restrict__ wts,
                  float* __restrict__ x, int Ntot)
{
    __shared__ float fs[ENB * EMBD];
    const int t = threadIdx.x;
    const int node0 = blockIdx.x * ENB;
    int nvalid = Ntot - node0;
    if (nvalid > ENB) nvalid = ENB;
    if (nvalid <= 0) return;
    const int lim = nvalid * EMBD;
    for (int d = t; d < lim; d += 256) fs[d] = fea[(size_t)node0 * EMBD + d];
    __syncthreads();

    const int nl = t >> 4;          // local node 0..15
    const int o  = t & 15;          // output column group
    if (nl >= nvalid) return;
    const int n = node0 + nl;

    float acc[4];
#pragma unroll
    for (int k2 = 0; k2 < 4; ++k2) {
        int oc = o + 16 * k2;
        acc[k2] = (oc < F - 1) ? b[oc] : wts[n];
    }
    const float* fsr = fs + nl * EMBD;
#pragma unroll 4
    for (int e = 0; e < EMBD; ++e) {
        float xv = fsr[e];                       // quad-broadcast LDS read
        const float* wr = W + (size_t)e * (F - 1);
#pragma unroll
        for (int k2 = 0; k2 < 4; ++k2) {
            int oc = o + 16 * k2;
            if (oc < F - 1) acc[k2] += xv * wr[oc];
        }
    }
#pragma unroll
    for (int k2 = 0; k2 < 4; ++k2)
        x[(size_t)n * F + o + 16 * k2] = acc[k2];
}

// ---------------------------------------------------------------------------
// One graph layer — barrier-free, 4 independent waves / block, each wave owns
// 3 crystals (15 nodes, 75 edges). GEMM2 B-frags hoisted. Wave LDS 12288 B.
// (256,2): round-10 proven — 2 blocks/CU, occupancy 18%, no spill.
//
// Round 11/12: instruction-diet, dataflow untouched.
//  - stage-1 MFMA operands SWAPPED: mfma(B_w, A_x) computes D[hid][node]
//    (A/B 16x16x32 frag lane-maps are identical, so the same swizzled
//    weights + x frags work). Each lane then holds 4 CONSECUTIVE hidden
//    values for one node -> 2x cvt_pkrtz + 1x ds_write_b64 replaces
//    4x v_cvt + 4x ds_write_b16 per nt. Consume-side PQ layout unchanged.
//  - gate dot via v_dot2_f32_f16: wg packed to f16 pairs once per chunk,
//    4 fdot2 per (et,ks) replaces 8 cvt + 8 fma.
// ---------------------------------------------------------------------------
#define WAVE_LDS 12288   // bytes per wave slice

__global__ __launch_bounds__(256, 2)
void layer_wave(float* __restrict__ x,
                const _Float16* __restrict__ W1sw,
                const _Float16* __restrict__ W2sw,
                const float* __restrict__ gb1, const float* __restrict__ gb2v,
                const float* __restrict__ mb1, const float* __restrict__ mb2,
                const float* __restrict__ gW2, const float* __restrict__ gpw,
                const float* __restrict__ wts, int l, int lhw0, int Ntot)
{
    __shared__ __align__(16) char smem[4 * WAVE_LDS];

    const int t = threadIdx.x, w = t >> 6, lane = t & 63;
    const int q = lane >> 4, m16 = lane & 15;

    char* wb = smem + w * WAVE_LDS;
    _Float16 (*PQ)[16][72] = (_Float16 (*)[16][72])wb;   // [4][16][72] = 9216 B
    _Float16 (*msgL)[72]   = (_Float16 (*)[72])wb;       // [80][72] = 11520 B (aliases PQ)
    float* gateS  = (float*)(wb + 11520);                // [80]
    float* anormS = (float*)(wb + 11840);                // [80]
    float* wpowS  = (float*)(wb + 12160);                // [16]

    const int nw0 = (blockIdx.x * 12 + w * CW) * K;      // first node of this wave
    const int vn  = (Ntot - nw0 < NWN) ? (Ntot - nw0) : NWN;  // valid nodes (may be <=0)

    // ---- A-fragments of x (head/half-invariant), fp16, loaded once ----
    half8 A[2];
    {
        int arow = nw0 + m16;
        if (arow > Ntot - 1) arow = Ntot - 1;            // clamp pad rows (finite junk)
        if (arow < 0) arow = 0;
        const float* xr = x + (size_t)arow * F;
#pragma unroll
        for (int ks = 0; ks < 2; ++ks) {
            float4 f0 = *(const float4*)(xr + ks * 32 + q * 8);
            float4 f1 = *(const float4*)(xr + ks * 32 + q * 8 + 4);
            half8 a;
            a[0] = (_Float16)f0.x; a[1] = (_Float16)f0.y;
            a[2] = (_Float16)f0.z; a[3] = (_Float16)f0.w;
            a[4] = (_Float16)f1.x; a[5] = (_Float16)f1.y;
            a[6] = (_Float16)f1.z; a[7] = (_Float16)f1.w;
            A[ks] = a;
        }
    }

    // ---- per-lane edge -> local node rows (75 valid edges in 5 tiles of 16) ----
    int iR[ET], jR[ET];
#pragma unroll
    for (int et = 0; et < ET; ++et) {
        int e = et * 16 + m16;
        if (e < EWE) {
            int cl = e / 25, rm = e % 25;
            iR[et] = cl * K + rm / K;
            jR[et] = cl * K + rm % K;
        } else { iR[et] = 15; jR[et] = 15; }             // pad row (clamped x, finite)
    }

    float oacc[NWN];
#pragma unroll
    for (int n = 0; n < NWN; ++n) oacc[n] = 0.f;

    for (int h = 0; h < NH; ++h) {
        const int lh = l * NH + h, lhw = lhw0 + h;

        if (lane < NWN) {
            int wi = nw0 + lane;
            if (wi > Ntot - 1) wi = Ntot - 1;
            if (wi < 0) wi = 0;
            wpowS[lane] = powf(wts[wi], gpw[lh]);
        }
        if (lane >= NWN && lane < NWN + 5) anormS[EWE + (lane - NWN)] = 0.f;  // pad slots 75..79

        f32x4 acc2[ET][4];
#pragma unroll
        for (int et = 0; et < ET; ++et)
#pragma unroll
            for (int nt = 0; nt < 4; ++nt) acc2[et][nt] = (f32x4){0.f, 0.f, 0.f, 0.f};
        float gacc[ET] = {0.f, 0.f, 0.f, 0.f, 0.f};

        for (int c = 0; c < 4; ++c) {
            // ---- GEMM2 B-frags for this chunk: issue early, reuse for 5 et ----
            half8 B2[8];
            {
                const _Float16* W2b = W2sw + ((size_t)lhw * 8 + c * 2) * 2048;
#pragma unroll
                for (int f = 0; f < 8; ++f)
                    B2[f] = *(const half8*)(W2b + ((size_t)f * 64 + lane) * 8);
            }

            // ---- stage-1: all 4 net-halves, TRANSPOSED mfma -> packed writes ----
#pragma unroll
            for (int hf = 0; hf < 4; ++hf) {
                f32x4 accS[4];
#pragma unroll
                for (int nt = 0; nt < 4; ++nt) accS[nt] = (f32x4){0.f, 0.f, 0.f, 0.f};
                const _Float16* Wb = W1sw + ((size_t)lhw * 4 + hf) * 16384 + c * 4096;
#pragma unroll
                for (int nt = 0; nt < 4; ++nt)
#pragma unroll
                    for (int ks = 0; ks < 2; ++ks) {
                        half8 B = *(const half8*)(Wb + ((nt * 2 + ks) * 64 + lane) * 8);
                        // swapped operands: D[hid][node]
                        accS[nt] = __builtin_amdgcn_mfma_f32_16x16x32_f16(
                            B, A[ks], accS[nt], 0, 0, 0);
                    }
                // lane holds hid = nt*16 + q*4 + rg for node = m16 -> one b64/nt
#pragma unroll
                for (int nt = 0; nt < 4; ++nt) {
                    h2 lo = cvt_pk(accS[nt][0], accS[nt][1]);
                    h2 hi = cvt_pk(accS[nt][2], accS[nt][3]);
                    h4 pk = __builtin_shufflevector(lo, hi, 0, 1, 2, 3);
                    *(h4*)&PQ[hf][m16][nt * 16 + q * 4] = pk;
                }
            }

            // ---- per-chunk bias slices (global, L1-hot); wg packed to f16 ----
            half8 bg8[2], bm8[2];
            h2 wgh2[2][4];
#pragma unroll
            for (int ks = 0; ks < 2; ++ks) {
                const int ub = c * 64 + ks * 32 + q * 8;
                float4 g0 = *(const float4*)(gb1 + (size_t)lh * HID + ub);
                float4 g1 = *(const float4*)(gb1 + (size_t)lh * HID + ub + 4);
                float4 m0 = *(const float4*)(mb1 + (size_t)lh * HID + ub);
                float4 m1 = *(const float4*)(mb1 + (size_t)lh * HID + ub + 4);
                float4 w0 = *(const float4*)(gW2 + (size_t)lh * HID + ub);
                float4 w1 = *(const float4*)(gW2 + (size_t)lh * HID + ub + 4);
                half8 bg, bm;
                bg[0]=(_Float16)g0.x; bg[1]=(_Float16)g0.y; bg[2]=(_Float16)g0.z; bg[3]=(_Float16)g0.w;
                bg[4]=(_Float16)g1.x; bg[5]=(_Float16)g1.y; bg[6]=(_Float16)g1.z; bg[7]=(_Float16)g1.w;
                bm[0]=(_Float16)m0.x; bm[1]=(_Float16)m0.y; bm[2]=(_Float16)m0.z; bm[3]=(_Float16)m0.w;
                bm[4]=(_Float16)m1.x; bm[5]=(_Float16)m1.y; bm[6]=(_Float16)m1.z; bm[7]=(_Float16)m1.w;
                bg8[ks] = bg; bm8[ks] = bm;
                wgh2[ks][0] = cvt_pk(w0.x, w0.y);
                wgh2[ks][1] = cvt_pk(w0.z, w0.w);
                wgh2[ks][2] = cvt_pk(w1.x, w1.y);
                wgh2[ks][3] = cvt_pk(w1.z, w1.w);
            }

            // ---- consume: gate fdot2 + hm A-frags + GEMM2 (B2 reused) ----
#pragma unroll
            for (int et = 0; et < ET; ++et) {
                half8 af[2];
#pragma unroll
                for (int ks = 0; ks < 2; ++ks) {
                    const int ub = ks * 32 + q * 8;
                    half8 pg = *(const half8*)&PQ[0][iR[et]][ub];
                    half8 qg = *(const half8*)&PQ[1][jR[et]][ub];
                    half8 pm = *(const half8*)&PQ[2][iR[et]][ub];
                    half8 qm = *(const half8*)&PQ[3][jR[et]][ub];
                    half8 tg = lrelu8(pg + qg + bg8[ks]);
                    h2 t01 = __builtin_shufflevector(tg, tg, 0, 1);
                    h2 t23 = __builtin_shufflevector(tg, tg, 2, 3);
                    h2 t45 = __builtin_shufflevector(tg, tg, 4, 5);
                    h2 t67 = __builtin_shufflevector(tg, tg, 6, 7);
                    gacc[et] = __builtin_amdgcn_fdot2(t01, wgh2[ks][0], gacc[et], false);
                    gacc[et] = __builtin_amdgcn_fdot2(t23, wgh2[ks][1], gacc[et], false);
                    gacc[et] = __builtin_amdgcn_fdot2(t45, wgh2[ks][2], gacc[et], false);
                    gacc[et] = __builtin_amdgcn_fdot2(t67, wgh2[ks][3], gacc[et], false);
                    af[ks] = lrelu8(pm + qm + bm8[ks]);
                }
#pragma unroll
                for (int nt = 0; nt < 4; ++nt)
#pragma unroll
                    for (int ks = 0; ks < 2; ++ks)
                        acc2[et][nt] = __builtin_amdgcn_mfma_f32_16x16x32_f16(
                            af[ks], B2[ks * 4 + nt], acc2[et][nt], 0, 0, 0);
            }
        }

        // ---- gate reduce across quads (k-slices) ----
        const float gb2s = gb2v[lh];
#pragma unroll
        for (int et = 0; et < ET; ++et) {
            float g = gacc[et];
            g += __shfl_xor(g, 16);
            g += __shfl_xor(g, 32);
            if (q == 0) gateS[et * 16 + m16] = g + gb2s;
        }

        // ---- segment softmax: lane n (0..14) handles local node n (5 edges) ----
        if (lane < NWN) {
            const int cl5 = (lane / K) * K;
            float gg[K], mx = -1e30f;
#pragma unroll
            for (int jj = 0; jj < K; ++jj) {
                gg[jj] = gateS[lane * K + jj];
                mx = fmaxf(mx, gg[jj]);
            }
            float s = 0.f, wv[K];
#pragma unroll
            for (int jj = 0; jj < K; ++jj) {
                wv[jj] = wpowS[cl5 + jj] * expf(gg[jj] - mx);
                s += wv[jj];
            }
            float inv = 1.f / (s + 1e-10f) * (1.f / 3.f);  // fold head mean
#pragma unroll
            for (int jj = 0; jj < K; ++jj) anormS[lane * K + jj] = wv[jj] * inv;
        }

        // ---- weighted msg -> msgL (PQ region dead) ----
        float b2v[4];
#pragma unroll
        for (int nt = 0; nt < 4; ++nt) b2v[nt] = mb2[(size_t)lh * F + nt * 16 + m16];
#pragma unroll
        for (int et = 0; et < ET; ++et) {
            f32x4 an = *(const f32x4*)&anormS[et * 16 + q * 4];
#pragma unroll
            for (int nt = 0; nt < 4; ++nt)
#pragma unroll
                for (int rg = 0; rg < 4; ++rg) {
                    float v = (acc2[et][nt][rg] + b2v[nt]) * an[rg];
                    msgL[et * 16 + q * 4 + rg][nt * 16 + m16] = (_Float16)v;
                }
        }

        // ---- aggregate: lane = output col, 15 nodes x 5 edges ----
#pragma unroll
        for (int n = 0; n < NWN; ++n) {
            float s = 0.f;
#pragma unroll
            for (int jj = 0; jj < K; ++jj) s += (float)msgL[n * K + jj][lane];
            oacc[n] += s;
        }
    }

    // ---- residual + write back (own valid rows only) ----
#pragma unroll
    for (int n = 0; n < NWN; ++n) {
        if (n < vn) {
            size_t idx = (size_t)(nw0 + n) * F + lane;
            x[idx] = oacc[n] + x[idx];
        }
    }
}

// ---------------------------------------------------------------------------
// MFMA pool (round-5 proven)
// ---------------------------------------------------------------------------
__global__ __launch_bounds__(256)
void pool_mfma(const float* __restrict__ x,
               const _Float16* __restrict__ cW1sw,
               const _Float16* __restrict__ cW2sw,
               const float* __restrict__ cgb1, const float* __restrict__ cgb2v,
               const float* __restrict__ cmb1, const float* __restrict__ cmb2,
               const float* __restrict__ cgW2, const float* __restrict__ cpw,
               const float* __restrict__ wts, float* __restrict__ out)
{
    __shared__ __align__(16) _Float16 xh[48][72];
    __shared__ __align__(16) char PQraw[2 * 48 * 72 * 2];
    __shared__ float outacc[CB * F];
    __shared__ float b1gS[HID], b1mS[HID], w2gS[HID], b2mS[F];
    __shared__ float gateS[48], anormS[48], wpowS[48];

    _Float16 (*P)[48][72] = (_Float16 (*)[48][72])PQraw;
    _Float16 (*msgW)[72]  = (_Float16 (*)[72])PQraw;

    const int t = threadIdx.x, w = t >> 6, lane = t & 63;
    const int quad = lane >> 4, m16 = lane & 15;
    const int node0 = blockIdx.x * NB;

    for (int d = t; d < 48 * 64; d += 256) {
        int r = d >> 6, cc = d & 63;
        float v = (r < NB) ? x[(size_t)(node0 + r) * F + cc] : 0.f;
        xh[r][cc] = (_Float16)v;
    }
    for (int d = t; d < CB * F; d += 256) outacc[d] = 0.f;
    __syncthreads();

    half8 A[3][2];
#pragma unroll
    for (int Mt = 0; Mt < 3; ++Mt)
#pragma unroll
        for (int ks = 0; ks < 2; ++ks)
            A[Mt][ks] = *(const half8*)&xh[Mt * 16 + m16][ks * 32 + quad * 8];

    const int net = w >> 1, ntp = w & 1;

    for (int h = 0; h < NH; ++h) {
        if (t < HID) {
            b1gS[t] = cgb1[(size_t)h * HID + t];
            b1mS[t] = cmb1[(size_t)h * HID + t];
            w2gS[t] = cgW2[(size_t)h * HID + t];
        }
        if (t < F)  b2mS[t] = cmb2[(size_t)h * F + t];
        if (t < NB) wpowS[t] = powf(wts[node0 + t], cpw[h]);
        const float gb2s = cgb2v[h];

        f32x4 acc2[4];
#pragma unroll
        for (int nt = 0; nt < 4; ++nt) acc2[nt] = (f32x4){0.f, 0.f, 0.f, 0.f};
        float gacc = 0.f;

        for (int chunk = 0; chunk < 4; ++chunk) {
            {
                f32x4 accS[3][2];
#pragma unroll
                for (int Mt = 0; Mt < 3; ++Mt)
#pragma unroll
                    for (int n2 = 0; n2 < 2; ++n2) accS[Mt][n2] = (f32x4){0.f, 0.f, 0.f, 0.f};
                const _Float16* Wb = cW1sw + ((size_t)(h * 2 + net) * 4 + chunk) * 4096;
#pragma unroll
                for (int n2 = 0; n2 < 2; ++n2) {
                    int nt = ntp * 2 + n2;
#pragma unroll
                    for (int ks = 0; ks < 2; ++ks) {
                        half8 B = *(const half8*)(Wb + ((nt * 2 + ks) * 64 + lane) * 8);
#pragma unroll
                        for (int Mt = 0; Mt < 3; ++Mt)
                            accS[Mt][n2] = __builtin_amdgcn_mfma_f32_16x16x32_f16(
                                A[Mt][ks], B, accS[Mt][n2], 0, 0, 0);
                    }
                }
#pragma unroll
                for (int Mt = 0; Mt < 3; ++Mt)
#pragma unroll
                    for (int n2 = 0; n2 < 2; ++n2)
#pragma unroll
                        for (int rg = 0; rg < 4; ++rg)
                            P[net][Mt * 16 + quad * 4 + rg][(ntp * 2 + n2) * 16 + m16] =
                                (_Float16)accS[Mt][n2][rg];
            }
            __syncthreads();

            if (w < 3) {
                half8 af[2];
#pragma unroll
                for (int ks = 0; ks < 2; ++ks) {
                    const int ub = ks * 32 + quad * 8;
                    half8 pg = *(const half8*)&P[0][w * 16 + m16][ub];
                    half8 pm = *(const half8*)&P[1][w * 16 + m16][ub];
#pragma unroll
                    for (int j = 0; j < 8; ++j) {
                        int u = chunk * 64 + ub + j;
                        float gh = lrelu((float)pg[j] + b1gS[u]);
                        gacc += gh * w2gS[u];
                        float hv = lrelu((float)pm[j] + b1mS[u]);
                        af[ks][j] = (_Float16)hv;
                    }
                }
                const _Float16* W2b = cW2sw + (size_t)h * 16384 + chunk * 4096;
#pragma unroll
                for (int nt = 0; nt < 4; ++nt)
#pragma unroll
                    for (int ks = 0; ks < 2; ++ks) {
                        half8 B = *(const half8*)(W2b + ((size_t)(ks * 4 + nt) * 64 + lane) * 8);
                        acc2[nt] = __builtin_amdgcn_mfma_f32_16x16x32_f16(
                            af[ks], B, acc2[nt], 0, 0, 0);
                    }
            }
            __syncthreads();
        }

        if (w < 3) {
            float g = gacc;
            g += __shfl_xor(g, 16);
            g += __shfl_xor(g, 32);
            if (quad == 0) gateS[w * 16 + m16] = g + gb2s;
        }
        __syncthreads();

        if (t < CB) {
            float mx = -1e30f;
#pragma unroll
            for (int j = 0; j < K; ++j) mx = fmaxf(mx, gateS[t * K + j]);
            float s = 0.f, wv[K];
#pragma unroll
            for (int j = 0; j < K; ++j) {
                wv[j] = wpowS[t * K + j] * expf(gateS[t * K + j] - mx);
                s += wv[j];
            }
            float inv = 1.f / (s + 1e-10f) * (1.f / 3.f);
#pragma unroll
            for (int j = 0; j < K; ++j) anormS[t * K + j] = wv[j] * inv;
        }
        __syncthreads();

        if (w < 3) {
#pragma unroll
            for (int nt = 0; nt < 4; ++nt)
#pragma unroll
                for (int rg = 0; rg < 4; ++rg) {
                    int row = w * 16 + quad * 4 + rg;
                    float a = (row < NB) ? anormS[row] : 0.f;
                    float v = (acc2[nt][rg] + b2mS[nt * 16 + m16]) * a;
                    msgW[row][nt * 16 + m16] = (_Float16)v;
                }
        }
        __syncthreads();

        for (int d = t; d < CB * F; d += 256) {
            int cr = d >> 6, o = d & 63;
            float s = 0.f;
#pragma unroll
            for (int j = 0; j < K; ++j) s += (float)msgW[cr * K + j][o];
            outacc[d] += s;
        }
        __syncthreads();
    }

    for (int d = t; d < CB * F; d += 256)
        out[(size_t)blockIdx.x * (CB * F) + d] = outacc[d];
}

// ---------------------------------------------------------------------------
// Fallback fp32 pool (round-4 proven)
// ---------------------------------------------------------------------------
__global__ __launch_bounds__(256)
void pool_kernel(const float* __restrict__ x,
                 const float* __restrict__ cgW1, const float* __restrict__ cgb1,
                 const float* __restrict__ cgW2, const float* __restrict__ cgb2,
                 const float* __restrict__ cmW1, const float* __restrict__ cmb1,
                 const float* __restrict__ cmW2, const float* __restrict__ cmb2,
                 const float* __restrict__ cpw, const float* __restrict__ wts,
                 float* __restrict__ out)
{
    __shared__ float xs[K * F];
    __shared__ float hmS[K][HID];
    __shared__ float msgS[K][F];
    __shared__ float outacc[F];
    __shared__ float b1g[HID], b1m[HID], w2g[HID];
    __shared__ float b2mS[F];
    __shared__ float gpart[K][2];
    __shared__ float gate_s[K];
    __shared__ float anorm[K];
    __shared__ float wn[K], wpow[K];

    const int c = blockIdx.x;
    const int t = threadIdx.x;
    const int wave = t >> 6, lane = t & 63;

    for (int d = t; d < K * F; d += 256) xs[d] = x[c * K * F + d];
    if (t < F) outacc[t] = 0.f;
    if (t < K) wn[t] = wts[c * K + t];
    __syncthreads();

    for (int h = 0; h < NH; ++h) {
        if (t < HID) {
            b1g[t] = cgb1[(size_t)h * HID + t];
            b1m[t] = cmb1[(size_t)h * HID + t];
            w2g[t] = cgW2[(size_t)h * HID + t];
        }
        if (t < F) b2mS[t] = cmb2[(size_t)h * F + t];
        if (t < K) wpow[t] = powf(wn[t], cpw[h]);
        __syncthreads();

        {
            const int grp = t >> 7;
            const int up  = t & 127;
            const float* Wb = (grp == 0 ? cgW1 : cmW1) + (size_t)h * F * HID;
            const float2* W2p = (const float2*)Wb;
            float acc[K][2];
#pragma unroll
            for (int i = 0; i < K; ++i) { acc[i][0] = 0.f; acc[i][1] = 0.f; }
            for (int k = 0; k < F; ++k) {
                float2 wv = W2p[k * (HID / 2) + up];
#pragma unroll
                for (int i = 0; i < K; ++i) {
                    float xv = xs[i * F + k];
                    acc[i][0] += xv * wv.x;
                    acc[i][1] += xv * wv.y;
                }
            }
            if (grp == 0) {
#pragma unroll
                for (int i = 0; i < K; ++i) {
                    float h0 = lrelu(acc[i][0] + b1g[2 * up]);
                    float h1 = lrelu(acc[i][1] + b1g[2 * up + 1]);
                    float part = h0 * w2g[2 * up] + h1 * w2g[2 * up + 1];
#pragma unroll
                    for (int s = 32; s; s >>= 1) part += __shfl_xor(part, s);
                    if (lane == 0) gpart[i][wave & 1] = part;
                }
            } else {
#pragma unroll
                for (int i = 0; i < K; ++i) {
                    hmS[i][2 * up]     = lrelu(acc[i][0] + b1m[2 * up]);
                    hmS[i][2 * up + 1] = lrelu(acc[i][1] + b1m[2 * up + 1]);
                }
            }
        }
        __syncthreads();
        if (t < K) gate_s[t] = cgb2[h] + gpart[t][0] + gpart[t][1];

        {
            const float2* W232 = (const float2*)(cmW2 + (size_t)h * HID * F);
            if (t < K * (F / 2)) {
                int i  = t >> 5;
                int op = t & 31;
                float a0 = b2mS[2 * op], a1 = b2mS[2 * op + 1];
#pragma unroll 8
                for (int u = 0; u < HID; ++u) {
                    float2 wv = W232[u * (F / 2) + op];
                    float hv = hmS[i][u];
                    a0 += hv * wv.x;
                    a1 += hv * wv.y;
                }
                msgS[i][2 * op]     = a0;
                msgS[i][2 * op + 1] = a1;
            }
        }
        __syncthreads();

        if (t == 0) {
            float mx = -1e30f;
#pragma unroll
            for (int i = 0; i < K; ++i) mx = fmaxf(mx, gate_s[i]);
            float wv[K], s = 0.f;
#pragma unroll
            for (int i = 0; i < K; ++i) {
                wv[i] = wpow[i] * expf(gate_s[i] - mx);
                s += wv[i];
            }
            float inv = 1.f / (s + 1e-10f);
#pragma unroll
            for (int i = 0; i < K; ++i) anorm[i] = wv[i] * inv;
        }
        __syncthreads();

        if (t < F) {
            float s = 0.f;
#pragma unroll
            for (int i = 0; i < K; ++i) s += anorm[i] * msgS[i][t];
            outacc[t] += s * (1.f / 3.f);
        }
        __syncthreads();
    }

    if (t < F) out[(size_t)c * F + t] = outacc[t];
}

// ---------------------------------------------------------------------------
extern "C" void kernel_launch(void* const* d_in, const int* in_sizes, int n_in,
                              void* d_out, int out_size, void* d_ws, size_t ws_size,
                              hipStream_t stream)
{
    const float* wts  = (const float*)d_in[0];
    const float* fea  = (const float*)d_in[1];
    const float* embW = (const float*)d_in[6];
    const float* embB = (const float*)d_in[7];
    const float* gW1  = (const float*)d_in[8];
    const float* gb1  = (const float*)d_in[9];
    const float* gW2  = (const float*)d_in[10];
    const float* gb2  = (const float*)d_in[11];
    const float* mW1  = (const float*)d_in[12];
    const float* mb1  = (const float*)d_in[13];
    const float* mW2  = (const float*)d_in[14];
    const float* mb2  = (const float*)d_in[15];
    const float* gpw  = (const float*)d_in[16];
    const float* cgW1 = (const float*)d_in[17];
    const float* cgb1 = (const float*)d_in[18];
    const float* cgW2 = (const float*)d_in[19];
    const float* cgb2 = (const float*)d_in[20];
    const float* cmW1 = (const float*)d_in[21];
    const float* cmb1 = (const float*)d_in[22];
    const float* cmW2 = (const float*)d_in[23];
    const float* cmb2 = (const float*)d_in[24];
    const float* cpw  = (const float*)d_in[25];

    const int N = in_sizes[0];   // 50000
    const int C = N / K;         // 10000
    const int layer_blocks = (C + 11) / 12;   // 834 (tail block guarded)

    float* x = (float*)d_ws;                       // [N,F] fp32, 12.8 MB
    const size_t xbytes = (size_t)N * F * 4;
    const size_t need = xbytes + (size_t)WALL_ELEMS * 2;

    embed_kernel<<<(N + ENB - 1) / ENB, 256, 0, stream>>>(fea, embW, embB, wts, x, N);

    if (ws_size >= need) {
        // ---- fast path ----
        _Float16* Wall  = (_Float16*)((char*)d_ws + xbytes);
        _Float16* W1sw  = Wall;
        _Float16* W2sw  = Wall + W1SW_ELEMS;
        _Float16* cW1sw = Wall + W1SW_ELEMS + W2SW_ELEMS;
        _Float16* cW2sw = Wall + W1SW_ELEMS + W2SW_ELEMS + CW1_ELEMS;

        prep_all<<<(WALL_ELEMS + 255) / 256, 256, 0, stream>>>(
            gW1, mW1, mW2, cgW1, cmW1, cmW2, Wall);
        for (int l = 0; l < NL; ++l)
            layer_wave<<<layer_blocks, 256, 0, stream>>>(x, W1sw, W2sw,
                                                         gb1, gb2, mb1, mb2, gW2, gpw, wts,
                                                         l, l * NH, N);
        pool_mfma<<<C / CB, 256, 0, stream>>>(x, cW1sw, cW2sw,
                                              cgb1, cgb2, cmb1, cmb2, cgW2, cpw, wts,
                                              (float*)d_out);
    } else {
        // ---- fallback: per-layer prep into d_out scratch ----
        _Float16* W1sw = (_Float16*)d_out;
        _Float16* W2sw = (_Float16*)((char*)d_out + 393216);
        for (int l = 0; l < NL; ++l) {
            prep_layer<<<(W1L_ELEMS + W2L_ELEMS) / 256, 256, 0, stream>>>(
                gW1, mW1, mW2, W1sw, W2sw, l);
            layer_wave<<<layer_blocks, 256, 0, stream>>>(x, W1sw, W2sw,
                                                         gb1, gb2, mb1, mb2, gW2, gpw, wts,
                                                         l, 0, N);
        }
        pool_kernel<<<C, 256, 0, stream>>>(x, cgW1, cgb1, cgW2, cgb2,
                                           cmW1, cmb1, cmW2, cmb2, cpw, wts,
                                           (float*)d_out);
    }
}